// Round 6
// baseline (181.567 us; speedup 1.0000x reference)
//
#include <hip/hip_runtime.h>
#include <cstdint>

#define NROI 2048
#define NCLS 21
#define NFG  20
#define CPAD 128          // candidate slots per class (>= top_k=100)
#define CTOT (NFG * CPAD) // 2560
#define TROW 512          // precomputed mask rows per class (sorted order)
#define CSEL 512          // contender cap for topk rank-count

typedef unsigned long long u64;
typedef unsigned int u32;

// ---- sortable key helpers -------------------------------------------------
// desc_key(s): larger float -> smaller uint, so ascending u64 sort ==
// (score descending, index ascending) when index is in the low 32 bits.
__device__ __forceinline__ u32 desc_key(float s) {
  u32 u = __float_as_uint(s);
  u32 asc = (u & 0x80000000u) ? ~u : (u | 0x80000000u);
  return ~asc;
}
__device__ __forceinline__ float key_to_float(u32 desc) {
  u32 asc = ~desc;
  u32 u = (asc & 0x80000000u) ? (asc ^ 0x80000000u) : ~asc;
  return __uint_as_float(u);
}
__device__ __forceinline__ u64 shfl_u64(u64 v, int src) {
  u32 lo = (u32)(v & 0xFFFFFFFFull);
  u32 hi = (u32)(v >> 32);
  lo = __shfl(lo, src);
  hi = __shfl(hi, src);
  return ((u64)hi << 32) | (u64)lo;
}
__device__ __forceinline__ float box_area(float4 b) {
  return __fmul_rn(__fsub_rn(b.z, b.x), __fsub_rn(b.w, b.y));
}
// IoU with row box bi (area ia) first — matches reference operand order.
__device__ __forceinline__ float iou_rn(float4 bi, float ia, float4 bj, float ab) {
  float lx = fmaxf(bi.x, bj.x), ly = fmaxf(bi.y, bj.y);
  float rx = fminf(bi.z, bj.z), ry = fminf(bi.w, bj.w);
  float w_ = fmaxf(__fsub_rn(rx, lx), 0.0f);
  float h_ = fmaxf(__fsub_rn(ry, ly), 0.0f);
  float inter = __fmul_rn(w_, h_);
  return __fdiv_rn(inter, __fsub_rn(__fadd_rn(ia, ab), inter));
}

// ---- phase 1: coalesced softmax + argmax + decode -------------------------
#define DROWS 256
__global__ __launch_bounds__(256)
void k_decode(const float* __restrict__ rois,
              const float* __restrict__ locs,
              const float* __restrict__ scores,
              float* __restrict__ probsT,     // [NFG][NROI]: class c+1 -> row c
              float4* __restrict__ decoded,
              u32* __restrict__ done) {
  __shared__ float srow[DROWS][NCLS + 2];   // stride 23 (odd) -> conflict-free
  const int tid = threadIdx.x;
  const int rbase = blockIdx.x * DROWS;
  if (rbase == 0 && tid == 0) *done = 0u;   // reset last-block counter each launch

  const float* src = scores + (size_t)rbase * NCLS;
  for (int t = tid; t < DROWS * NCLS; t += 256)
    srow[t / NCLS][t % NCLS] = src[t];
  __syncthreads();

  const int r = rbase + tid;
  float s[NCLS];
  #pragma unroll
  for (int c = 0; c < NCLS; ++c) s[c] = srow[tid][c];
  float m = s[0];
  #pragma unroll
  for (int c = 0; c < NCLS; ++c) m = fmaxf(m, s[c]);
  float sum = 0.0f;
  #pragma unroll
  for (int c = 0; c < NCLS; ++c) { s[c] = expf(s[c] - m); sum += s[c]; }

  float pb = s[0] / sum; int best = 0;
  #pragma unroll
  for (int c = 1; c < NCLS; ++c) {
    float p = s[c] / sum;
    probsT[(c - 1) * NROI + r] = p;        // coalesced store per class
    if (p > pb) { pb = p; best = c; }      // strict > == first-index argmax
  }

  float4 roi = ((const float4*)rois)[r];
  float pcx = __fmul_rn(__fadd_rn(roi.x, roi.z), 0.5f);
  float pcy = __fmul_rn(__fadd_rn(roi.y, roi.w), 0.5f);
  float pw  = __fsub_rn(roi.z, roi.x);
  float ph  = __fsub_rn(roi.w, roi.y);

  float4 gl = ((const float4*)locs)[r * NCLS + best];   // 16B-aligned
  float g0 = gl.x / 10.0f;
  float g1 = gl.y / 10.0f;
  float g2 = gl.z / 20.0f;
  float g3 = gl.w / 20.0f;

  float cx = __fadd_rn(__fmul_rn(g0, pw), pcx);
  float cy = __fadd_rn(__fmul_rn(g1, ph), pcy);
  float w  = __fmul_rn(expf(g2), pw);
  float h  = __fmul_rn(expf(g3), ph);
  float hw = __fmul_rn(w, 0.5f);
  float hh = __fmul_rn(h, 0.5f);
  decoded[r] = make_float4(__fsub_rn(cx, hw), __fsub_rn(cy, hh),
                           __fadd_rn(cx, hw), __fadd_rn(cy, hh));
}

// ---- phase 2: per-class bitonic sort of keys ------------------------------
__global__ __launch_bounds__(1024)
void k_sel(const float* __restrict__ probsT,
           const float* __restrict__ min_score_p,
           u64* __restrict__ skey,
           int* __restrict__ nvalid) {
  __shared__ u64 keys[NROI];        // 16 KB
  __shared__ int cntLds;
  const int cls = blockIdx.x;
  const int tid = threadIdx.x;
  const float msc = *min_score_p;
  if (tid == 0) cntLds = 0;
  __syncthreads();

  int local = 0;
  for (int i = tid; i < NROI; i += 1024) {
    float p = probsT[cls * NROI + i];
    bool valid = p > msc;
    local += valid ? 1 : 0;
    float keyf = valid ? p : -__builtin_inff();
    keys[i] = ((u64)desc_key(keyf) << 32) | (u32)i;
  }
  atomicAdd(&cntLds, local);
  __syncthreads();

  // one pair/thread/pass; wave-local phases (j<=64) skip the full barrier
  for (int k = 2; k <= NROI; k <<= 1) {
    for (int j = k >> 1; j > 0; j >>= 1) {
      if (j > 64 || (j == 64 && k > 128)) __syncthreads();
      else asm volatile("s_waitcnt lgkmcnt(0)" ::: "memory");
      int lo = tid & (j - 1);
      int i = ((tid & ~(j - 1)) << 1) | lo;
      int ixj = i | j;
      u64 a = keys[i], b = keys[ixj];
      bool up = ((i & k) == 0);
      if ((a > b) == up) { keys[i] = b; keys[ixj] = a; }
    }
  }
  __syncthreads();

  for (int i = tid; i < NROI; i += 1024)
    skey[(size_t)cls * NROI + i] = keys[i];
  if (tid == 0) nvalid[cls] = cntLds;
}

// ---- phase 3: suppression masks (top-TROW sorted rows x ALL orig cols) ----
// grid: NFG*8 blocks x 256 threads; block owns 256 original columns.
__global__ __launch_bounds__(256)
void k_mask(const float* __restrict__ probsT,
            const float4* __restrict__ decoded,
            const u64* __restrict__ skey,
            const int* __restrict__ nvalid,
            const float* __restrict__ min_score_p,
            const float* __restrict__ max_overlap_p,
            u64* __restrict__ maskG) {
  __shared__ float4 rbox[64];
  __shared__ u64 rkey[64];
  const int c = blockIdx.x >> 3;
  const int chunk = blockIdx.x & 7;
  const int tid = threadIdx.x;
  const int lane = tid & 63;
  const int wid = tid >> 6;
  const float msc = *min_score_p;
  const float ovr = *max_overlap_p;
  const int nv = nvalid[c];
  const int Rmax = (nv < TROW) ? nv : TROW;

  const int j = chunk * 256 + tid;          // original column index
  float p = probsT[c * NROI + j];
  bool valid = p > msc;
  float keyf = valid ? p : -__builtin_inff();
  u64 ckey = ((u64)desc_key(keyf) << 32) | (u32)j;
  float4 bj = decoded[j];
  float ab = box_area(bj);

  for (int t0 = 0; t0 < Rmax; t0 += 64) {
    __syncthreads();
    if (tid < 64) {
      int r = t0 + tid;
      u64 k0 = 0; float4 bb = make_float4(0.f, 0.f, 0.f, 0.f);
      if (r < Rmax) { k0 = skey[(size_t)c * NROI + r]; bb = decoded[(u32)k0]; }
      rkey[tid] = k0; rbox[tid] = bb;
    }
    __syncthreads();
    int rlim = Rmax - t0; if (rlim > 64) rlim = 64;
    for (int q = 0; q < rlim; ++q) {
      float4 bi = rbox[q];
      u64 rk = rkey[q];
      float ia = box_area(bi);
      float iou = iou_rn(bi, ia, bj, ab);
      bool bit = (iou > ovr) && (ckey > rk);
      u64 bal = __ballot(bit);
      if (lane == 0)
        maskG[((size_t)(c * TROW + t0 + q)) * 32 + (chunk * 4 + wid)] = bal;
    }
  }
}

// ---- phase 4: per-class greedy sweep + compact + fused global top-K -------
__global__ __launch_bounds__(1024)
void k_sweep(const float* __restrict__ probsT,
             const float4* __restrict__ decoded,
             const u64* __restrict__ skey,
             const u64* __restrict__ maskG,
             const int* __restrict__ nvalid,
             const float* __restrict__ min_score_p,
             const float* __restrict__ max_overlap_p,
             u64* __restrict__ cand,
             float4* __restrict__ cbox,
             u32* __restrict__ done,
             float* __restrict__ out,
             const int* __restrict__ top_k_p) {
  __shared__ u64 skLds[TROW];          // 4 KB sorted keys (first TROW)
  __shared__ u32 rem32[NROI / 32];     // removed bitmap over ORIGINAL indices
  __shared__ u32 survLds[CPAD];        // surviving sorted-row positions
  __shared__ int scLds, rNextLds;
  __shared__ u32 lastSh;
  // fused top-k
  __shared__ u64 kk[CTOT];             // 20 KB
  __shared__ int hist1[256], hist2[256];
  __shared__ int selB1, selC1, selB2, mSh, cCnt;
  __shared__ u64 ckeys[CSEL];

  const int c = blockIdx.x;
  const int tid = threadIdx.x;
  const int lane = tid & 63;
  const int wid = tid >> 6;
  const float msc = *min_score_p;
  const float ovr = *max_overlap_p;
  const int nv = nvalid[c];
  const int K = *top_k_p;
  const int Kcap = (K < CPAD) ? K : CPAD;
  const int Rmax = (nv < TROW) ? nv : TROW;

  if (tid < TROW) skLds[tid] = skey[(size_t)c * NROI + tid];
  #pragma unroll
  for (int it = 0; it < 2; ++it) {
    int i = it * 1024 + tid;
    float p = probsT[c * NROI + i];
    u64 b = __ballot(!(p > msc));      // removed = invalid
    if (lane == 0) {
      int w0 = it * 32 + wid * 2;
      rem32[w0] = (u32)b;
      rem32[w0 + 1] = (u32)(b >> 32);
    }
  }
  if (tid == 0) { scLds = 0; rNextLds = Rmax; }
  __syncthreads();

  // ---- wave-0 sweep over precomputed mask rows (8-deep double-buffer) ----
  if (wid == 0) {
    u64 rw = 0;
    if (lane < 32) rw = ((u64)rem32[2 * lane + 1] << 32) | (u64)rem32[2 * lane];
    int sc = 0;
    u64 mA[8], mB[8];
    #pragma unroll
    for (int q = 0; q < 8; ++q)
      mA[q] = (lane < 32 && q < Rmax)
                  ? maskG[((size_t)(c * TROW + q)) * 32 + lane] : 0ULL;
    for (int base = 0; base < Rmax; base += 8) {
      #pragma unroll
      for (int q = 0; q < 8; ++q) {
        int rn = base + 8 + q;
        mB[q] = (lane < 32 && rn < Rmax)
                    ? maskG[((size_t)(c * TROW + rn)) * 32 + lane] : 0ULL;
      }
      #pragma unroll
      for (int q = 0; q < 8; ++q) {
        int r = base + q;
        if (r < Rmax && sc < Kcap) {
          u32 orig = (u32)skLds[r];
          u64 w = shfl_u64(rw, (int)(orig >> 6));   // wave-uniform src
          if (!((w >> (orig & 63)) & 1ULL)) {       // alive -> survivor
            rw |= mA[q];
            if (lane == 0) survLds[sc] = (u32)r;
            ++sc;
          }
        }
      }
      if (sc >= Kcap) break;
      #pragma unroll
      for (int q = 0; q < 8; ++q) mA[q] = mB[q];
    }
    if (lane < 32) { rem32[2 * lane] = (u32)rw; rem32[2 * lane + 1] = (u32)(rw >> 32); }
    if (lane == 0) scLds = sc;
  }
  __syncthreads();

  // ---- exact cold-path extension for rows beyond TROW (rarely taken) ----
  while (true) {
    __syncthreads();
    int scNow = scLds, rN = rNextLds;
    if (scNow >= Kcap || rN >= nv) break;
    u64 rkeyv = skey[(size_t)c * NROI + rN];       // uniform broadcast load
    u32 orig = (u32)rkeyv;
    bool alive = !((rem32[orig >> 5] >> (orig & 31)) & 1u);
    if (alive) {
      float4 bi = decoded[orig];
      float ia = box_area(bi);
      #pragma unroll
      for (int it = 0; it < 2; ++it) {
        int jj = it * 1024 + tid;
        float pj = probsT[c * NROI + jj];
        u64 ck = ((u64)desc_key((pj > msc) ? pj : -__builtin_inff()) << 32) | (u32)jj;
        float4 bb = decoded[jj];
        float ab = box_area(bb);
        float iou = iou_rn(bi, ia, bb, ab);
        if ((iou > ovr) && (ck > rkeyv))
          atomicOr(&rem32[jj >> 5], 1u << (jj & 31));
      }
    }
    __syncthreads();
    if (tid == 0) {
      if (alive) { survLds[scLds] = (u32)rN; scLds = scLds + 1; }
      rNextLds = rN + 1;
    }
  }
  __syncthreads();

  // ---- emit per-class survivors (sorted order) ----
  int scf = scLds; if (scf > Kcap) scf = Kcap;
  if (tid < CPAD) {
    int o = c * CPAD + tid;
    if (tid < scf) {
      int r = (int)survLds[tid];
      u64 key = (r < TROW) ? skLds[r] : skey[(size_t)c * NROI + r];
      cand[o] = (key & 0xFFFFFFFF00000000ULL) | (u32)o;  // low32 == tie-order
      cbox[o] = decoded[(u32)key];
    } else {
      cand[o] = ~0ULL;
    }
  }

  // ---- last block does the global top-K ----
  __threadfence();
  __syncthreads();
  if (tid == 0) lastSh = atomicAdd(done, 1u);
  __syncthreads();
  if (lastSh != NFG - 1) return;
  __threadfence();

  if (tid == 0) { mSh = 0; cCnt = 0; }
  if (tid < 256) { hist1[tid] = 0; hist2[tid] = 0; }
  __syncthreads();
  int np = 0;
  for (int t = tid; t < CTOT; t += 1024) {
    u64 v = cand[t];
    kk[t] = v;
    if (v != ~0ULL) { ++np; atomicAdd(&hist1[(int)(v >> 56)], 1); }
  }
  atomicAdd(&mSh, np);
  __syncthreads();
  const int M = mSh;
  const int Kneed = (K < M) ? K : M;

  if (Kneed > 0) {
    if (tid == 0) {               // level-1 boundary bucket
      int cum = 0, b = 0;
      while (cum + hist1[b] < Kneed) { cum += hist1[b]; ++b; }
      selB1 = b; selC1 = cum;
    }
    __syncthreads();
    const int B1 = selB1, C1 = selC1;
    for (int t = tid; t < CTOT; t += 1024) {
      u64 v = kk[t];
      if (v != ~0ULL && (int)(v >> 56) == B1)
        atomicAdd(&hist2[(int)((v >> 48) & 255)], 1);
    }
    __syncthreads();
    if (tid == 0) {               // level-2 boundary bucket
      int need2 = Kneed - C1;
      int cum = 0, b = 0;
      while (cum + hist2[b] < need2) { cum += hist2[b]; ++b; }
      selB2 = b;
    }
    __syncthreads();
    const int B2 = selB2;
    for (int t = tid; t < CTOT; t += 1024) {   // compact contenders
      u64 v = kk[t];
      if (v == ~0ULL) continue;
      int b1 = (int)(v >> 56);
      int b2 = (int)((v >> 48) & 255);
      if (b1 < B1 || (b1 == B1 && b2 <= B2)) {
        int pos = atomicAdd(&cCnt, 1);
        if (pos < CSEL) ckeys[pos] = v;
      }
    }
    __syncthreads();
    const int C = cCnt;
    if (C <= CSEL) {
      // contender set is downward-closed -> rank among contenders == global rank
      if (tid < C) {
        u64 my = ckeys[tid];
        int rank = 0;
        for (int u = 0; u < C; ++u) rank += (ckeys[u] < my) ? 1 : 0;
        if (rank < Kneed) {
          u32 flat = (u32)(my & 0xFFFFFFFFu);
          float score = key_to_float((u32)(my >> 32));
          int cls2 = (int)(flat >> 7);
          float4 b = cbox[flat];
          out[rank * 4 + 0] = b.x;
          out[rank * 4 + 1] = b.y;
          out[rank * 4 + 2] = b.z;
          out[rank * 4 + 3] = b.w;
          out[K * 4 + rank] = (float)(cls2 + 1);
          out[K * 5 + rank] = score;
        }
      }
    } else {
      // paranoia fallback: exact rank via 20 per-class binary searches
      for (int t = tid; t < CTOT; t += 1024) {
        u64 kap = kk[t];
        if (kap == ~0ULL) continue;
        int rank = 0;
        #pragma unroll
        for (int cc2 = 0; cc2 < NFG; ++cc2) {
          const u64* a = kk + cc2 * CPAD;
          int lb = 0;
          #pragma unroll
          for (int s2 = CPAD >> 1; s2; s2 >>= 1) {
            int pq = lb + s2;
            if (a[pq - 1] < kap) lb = pq;
          }
          rank += lb;
        }
        if (rank < Kneed) {
          u32 flat = (u32)(kap & 0xFFFFFFFFu);
          float score = key_to_float((u32)(kap >> 32));
          int cls2 = (int)(flat >> 7);
          float4 b = cbox[flat];
          out[rank * 4 + 0] = b.x;
          out[rank * 4 + 1] = b.y;
          out[rank * 4 + 2] = b.z;
          out[rank * 4 + 3] = b.w;
          out[K * 4 + rank] = (float)(cls2 + 1);
          out[K * 5 + rank] = score;
        }
      }
    }
  }
  __syncthreads();
  for (int r = tid; r < K; r += 1024) {
    if (r >= M) {
      out[r * 4 + 0] = 0.0f; out[r * 4 + 1] = 0.0f;
      out[r * 4 + 2] = 1.0f; out[r * 4 + 3] = 1.0f;
      out[K * 4 + r] = 0.0f;
      out[K * 5 + r] = 0.0f;
    }
  }
}

// ---- launch ---------------------------------------------------------------
extern "C" void kernel_launch(void* const* d_in, const int* in_sizes, int n_in,
                              void* d_out, int out_size, void* d_ws, size_t ws_size,
                              hipStream_t stream) {
  const float* rois        = (const float*)d_in[0];
  const float* locs        = (const float*)d_in[1];
  const float* scores      = (const float*)d_in[2];
  const float* min_score   = (const float*)d_in[3];
  const float* max_overlap = (const float*)d_in[4];
  const int*   top_k       = (const int*)d_in[5];

  char* ws = (char*)d_ws;
  const size_t off_probsT  = 0;                                   // 163840
  const size_t off_decoded = off_probsT + (size_t)NFG * NROI * 4; // +32768
  const size_t off_skey    = off_decoded + (size_t)NROI * 16;     // +327680
  const size_t off_mask    = off_skey + (size_t)NFG * NROI * 8;   // +2621440
  const size_t off_cand    = off_mask + (size_t)NFG * TROW * 32 * 8; // +20480
  const size_t off_cbox    = off_cand + (size_t)CTOT * 8;         // +40960
  const size_t off_nvalid  = off_cbox + (size_t)CTOT * 16;        // +128
  const size_t off_done    = off_nvalid + 128;

  float*  probsT  = (float*)(ws + off_probsT);
  float4* decoded = (float4*)(ws + off_decoded);
  u64*    skey    = (u64*)(ws + off_skey);
  u64*    maskG   = (u64*)(ws + off_mask);
  u64*    cand    = (u64*)(ws + off_cand);
  float4* cbox    = (float4*)(ws + off_cbox);
  int*    nvalid  = (int*)(ws + off_nvalid);
  u32*    done    = (u32*)(ws + off_done);

  k_decode<<<NROI / DROWS, 256, 0, stream>>>(rois, locs, scores, probsT, decoded, done);
  k_sel<<<NFG, 1024, 0, stream>>>(probsT, min_score, skey, nvalid);
  k_mask<<<NFG * 8, 256, 0, stream>>>(probsT, decoded, skey, nvalid,
                                      min_score, max_overlap, maskG);
  k_sweep<<<NFG, 1024, 0, stream>>>(probsT, decoded, skey, maskG, nvalid,
                                    min_score, max_overlap,
                                    cand, cbox, done, (float*)d_out, top_k);
}

// Round 7
// 102.816 us; speedup vs baseline: 1.7659x; 1.7659x over previous
//
#include <hip/hip_runtime.h>
#include <cstdint>

#define NROI 2048
#define NCLS 21
#define NFG  20
#define CPAD 128          // survivor slots per class (>= top_k=100)
#define CTOT (NFG * CPAD) // 2560
#define NTHR 1024         // threads per NMS block (16 waves)
#define DROWS 256         // rows per decode block

typedef unsigned long long u64;
typedef unsigned int u32;

// ---- sortable key helpers -------------------------------------------------
// desc_key(s): larger float -> smaller uint, so ascending sort on
// (keyH, keyL=index) == (score descending, index ascending).
__device__ __forceinline__ u32 desc_key(float s) {
  u32 u = __float_as_uint(s);
  u32 asc = (u & 0x80000000u) ? ~u : (u | 0x80000000u);
  return ~asc;
}
__device__ __forceinline__ float key_to_float(u32 desc) {
  u32 asc = ~desc;
  u32 u = (asc & 0x80000000u) ? (asc ^ 0x80000000u) : ~asc;
  return __uint_as_float(u);
}
__device__ __forceinline__ u64 shfl_u64(u64 v, int src) {
  u32 lo = (u32)(v & 0xFFFFFFFFull);
  u32 hi = (u32)(v >> 32);
  lo = __shfl(lo, src);
  hi = __shfl(hi, src);
  return ((u64)hi << 32) | (u64)lo;
}

// ---- phase 1: coalesced softmax + argmax + decode -------------------------
__global__ __launch_bounds__(256)
void k_decode(const float* __restrict__ rois,
              const float* __restrict__ locs,
              const float* __restrict__ scores,
              float* __restrict__ probsT,     // [NFG][NROI]: class c+1 -> row c
              float4* __restrict__ decoded,
              u32* __restrict__ done) {
  __shared__ float srow[DROWS][NCLS + 2];   // stride 23 (odd) -> conflict-free
  const int tid = threadIdx.x;
  const int rbase = blockIdx.x * DROWS;
  if (rbase == 0 && tid == 0) *done = 0u;   // reset last-block counter each launch

  const float* src = scores + (size_t)rbase * NCLS;
  for (int t = tid; t < DROWS * NCLS; t += 256)
    srow[t / NCLS][t % NCLS] = src[t];
  __syncthreads();

  const int r = rbase + tid;
  float s[NCLS];
  #pragma unroll
  for (int c = 0; c < NCLS; ++c) s[c] = srow[tid][c];
  float m = s[0];
  #pragma unroll
  for (int c = 0; c < NCLS; ++c) m = fmaxf(m, s[c]);
  float sum = 0.0f;
  #pragma unroll
  for (int c = 0; c < NCLS; ++c) { s[c] = expf(s[c] - m); sum += s[c]; }

  float pb = s[0] / sum; int best = 0;
  #pragma unroll
  for (int c = 1; c < NCLS; ++c) {
    float p = s[c] / sum;
    probsT[(c - 1) * NROI + r] = p;        // coalesced store per class
    if (p > pb) { pb = p; best = c; }      // strict > == first-index argmax
  }

  float4 roi = ((const float4*)rois)[r];
  float pcx = __fmul_rn(__fadd_rn(roi.x, roi.z), 0.5f);
  float pcy = __fmul_rn(__fadd_rn(roi.y, roi.w), 0.5f);
  float pw  = __fsub_rn(roi.z, roi.x);
  float ph  = __fsub_rn(roi.w, roi.y);

  float4 gl = ((const float4*)locs)[r * NCLS + best];   // 16B-aligned
  float g0 = gl.x / 10.0f;
  float g1 = gl.y / 10.0f;
  float g2 = gl.z / 20.0f;
  float g3 = gl.w / 20.0f;

  // no-FMA-contraction decode to match numpy rounding
  float cx = __fadd_rn(__fmul_rn(g0, pw), pcx);
  float cy = __fadd_rn(__fmul_rn(g1, ph), pcy);
  float w  = __fmul_rn(expf(g2), pw);
  float h  = __fmul_rn(expf(g3), ph);
  float hw = __fmul_rn(w, 0.5f);
  float hh = __fmul_rn(h, 0.5f);
  decoded[r] = make_float4(__fsub_rn(cx, hw), __fsub_rn(cy, hh),
                           __fadd_rn(cx, hw), __fadd_rn(cy, hh));
}

// ---- phase 2: per-class sort + greedy NMS + last-block top-k --------------
__global__ __launch_bounds__(NTHR)
void k_nms(const float* __restrict__ probsT,
           const float4* __restrict__ decoded,
           const float* __restrict__ min_score_p,
           const float* __restrict__ max_overlap_p,
           u64* __restrict__ cand,
           float4* __restrict__ cbox,
           u32* __restrict__ done,
           float* __restrict__ out,
           const int* __restrict__ top_k_p) {
  __shared__ u32 keyH[NROI];        // 8 KB  (SoA split: 4B accesses keep all
  __shared__ u32 keyL[NROI];        // 8 KB   bitonic passes <=2-way on banks)
  __shared__ float4 sbox[NROI];     // 32 KB (reused as kk[2560] for topk)
  __shared__ u32 rem32[NROI / 32];  // removed bitmap (sorted order)
  __shared__ u32 gm32[128];         // group 64x64 suppression matrix
  __shared__ int survLds[CPAD];
  __shared__ u64 aliveShared;
  __shared__ int scountLds, cntLds;
  __shared__ u32 lastSh;

  const int cls = blockIdx.x;
  const int tid = threadIdx.x;
  const int lane = tid & 63;
  const int wid = tid >> 6;
  const float msc = *min_score_p;
  const float ovr = *max_overlap_p;
  const int K = *top_k_p;
  const int Kcap = (K < CPAD) ? K : CPAD;

  if (tid == 0) { cntLds = 0; scountLds = 0; }
  __syncthreads();

  // ---- keys from this class's prob column (coalesced 8 KB) ----
  int local = 0;
  for (int i = tid; i < NROI; i += NTHR) {
    float p = probsT[cls * NROI + i];
    bool valid = p > msc;
    local += valid ? 1 : 0;
    float keyf = valid ? p : -__builtin_inff();
    keyH[i] = desc_key(keyf);
    keyL[i] = (u32)i;
  }
  atomicAdd(&cntLds, local);
  __syncthreads();

  // ---- bitonic sort: one pair/thread/pass; wave-local phases skip barrier --
  // For j<=64, wave w's pairs stay inside its private segment [128w,128w+128):
  // i(t)=((t&~(j-1))<<1)|(t&(j-1)). Full barrier only for cross-wave phases
  // (j>64) and at the cross->intra transition (j==64 && k>128).
  for (int k = 2; k <= NROI; k <<= 1) {
    for (int j = k >> 1; j > 0; j >>= 1) {
      if (j > 64 || (j == 64 && k > 128)) __syncthreads();
      else asm volatile("s_waitcnt lgkmcnt(0)" ::: "memory");
      int lo = tid & (j - 1);
      int i = ((tid & ~(j - 1)) << 1) | lo;
      int ixj = i | j;
      u32 ah = keyH[i], al = keyL[i];
      u32 bh = keyH[ixj], bl = keyL[ixj];
      bool agtb = (ah > bh) || (ah == bh && al > bl);  // keys unique overall
      bool up = ((i & k) == 0);
      if (agtb == up) {
        keyH[i] = bh; keyL[i] = bl;
        keyH[ixj] = ah; keyL[ixj] = al;
      }
    }
  }
  __syncthreads();

  const int nv = cntLds;

  // ---- gather boxes into sorted order (scattered float4, cheap) ----
  for (int i = tid; i < NROI; i += NTHR) {
    int orig = (int)keyL[i];
    sbox[i] = decoded[orig];
  }
  for (int w = tid; w < NROI / 32; w += NTHR) {
    int start = nv - w * 32;
    rem32[w] = (start <= 0) ? 0xFFFFFFFFu : ((start >= 32) ? 0u : (0xFFFFFFFFu << start));
  }
  __syncthreads();

  // ---- greedy NMS in 64-row groups ----
  int sc = 0;
  const int ng = (nv + 63) >> 6;
  for (int g = 0; g < ng; ++g) {
    if (tid < 128) gm32[tid] = 0;
    __syncthreads();
    {
      const int i = tid >> 4;               // row within group
      const int c0 = (tid & 15) << 2;       // 4 cols within group
      float4 bi = sbox[(g << 6) + i];
      float ia = __fmul_rn(__fsub_rn(bi.z, bi.x), __fsub_rn(bi.w, bi.y));
      u32 nib = 0;
      #pragma unroll
      for (int q = 0; q < 4; ++q) {
        int jj = c0 + q;
        if (jj > i) {
          float4 bj = sbox[(g << 6) + jj];
          float lx = fmaxf(bi.x, bj.x), ly = fmaxf(bi.y, bj.y);
          float rx = fminf(bi.z, bj.z), ry = fminf(bi.w, bj.w);
          float w_ = fmaxf(__fsub_rn(rx, lx), 0.0f);
          float h_ = fmaxf(__fsub_rn(ry, ly), 0.0f);
          float inter = __fmul_rn(w_, h_);
          float ab = __fmul_rn(__fsub_rn(bj.z, bj.x), __fsub_rn(bj.w, bj.y));
          float iou = __fdiv_rn(inter, __fsub_rn(__fadd_rn(ia, ab), inter));
          if (iou > ovr) nib |= (1u << (jj & 31));
        }
      }
      if (nib) atomicOr(&gm32[(i << 1) + (c0 >> 5)], nib);
    }
    __syncthreads();

    // greedy closure over the 64-bit group (wave 0)
    if (wid == 0) {
      u64 mrow = ((u64)gm32[(lane << 1) + 1] << 32) | (u64)gm32[lane << 1];
      u64 alive = ~(((u64)rem32[(g << 1) + 1] << 32) | (u64)rem32[g << 1]);
      u64 pend = alive;
      while (pend) {
        int i = __ffsll((long long)pend) - 1;
        pend &= pend - 1;
        u64 mi = shfl_u64(mrow, i);          // bits > i only
        alive &= ~mi;
        pend  &= ~mi;
      }
      int base = sc;
      if ((alive >> lane) & 1ULL) {
        int rank = base + __popcll(alive & ((1ULL << lane) - 1ULL));
        if (rank < CPAD) survLds[rank] = (g << 6) + lane;
      }
      sc = base + __popcll(alive);
      if (lane == 0) { scountLds = sc; aliveShared = alive; }
    }
    __syncthreads();
    u64 aw = aliveShared;
    sc = scountLds;
    if (sc >= Kcap) break;    // uniform; per-class rank>=K can't reach top-K

    // suppress later columns by this group's survivors (2 cols per thread)
    const int colbase = (g + 1) << 6;
    if (aw != 0ULL && colbase < nv) {
      #pragma unroll
      for (int ss = 0; ss < 2; ++ss) {
        int j = colbase + ss * NTHR + tid;
        bool inr = j < nv;
        bool act = false;
        float4 bj; float ab = 0.0f;
        if (inr) {
          act = !((rem32[j >> 5] >> (j & 31)) & 1u);
          bj = sbox[j];
          ab = __fmul_rn(__fsub_rn(bj.z, bj.x), __fsub_rn(bj.w, bj.y));
        }
        bool kill = false;
        u64 t = aw;                       // wave-uniform loop
        while (t) {
          int b = __ffsll((long long)t) - 1;
          t &= t - 1;
          float4 bi = sbox[(g << 6) + b]; // LDS broadcast
          if (act && !kill) {
            float ia = __fmul_rn(__fsub_rn(bi.z, bi.x), __fsub_rn(bi.w, bi.y));
            float lx = fmaxf(bi.x, bj.x), ly = fmaxf(bi.y, bj.y);
            float rx = fminf(bi.z, bj.z), ry = fminf(bi.w, bj.w);
            float w_ = fmaxf(__fsub_rn(rx, lx), 0.0f);
            float h_ = fmaxf(__fsub_rn(ry, ly), 0.0f);
            float inter = __fmul_rn(w_, h_);
            float iou = __fdiv_rn(inter, __fsub_rn(__fadd_rn(ia, ab), inter));
            kill = iou > ovr;
          }
        }
        u64 bal = __ballot(kill);
        if (lane == 0 && bal != 0ULL) {
          int j0 = colbase + ss * NTHR + (wid << 6);   // 64-aligned wave base
          u32 loB = (u32)bal, hiB = (u32)(bal >> 32);
          if (loB) atomicOr(&rem32[j0 >> 5], loB);
          if (hiB) atomicOr(&rem32[(j0 >> 5) + 1], hiB);
        }
      }
    }
    __syncthreads();
  }
  __syncthreads();

  // ---- emit per-class survivor list (sorted; segments strictly ascending) --
  int scf = scountLds; if (scf > Kcap) scf = Kcap;
  if (tid < CPAD) {
    int o = cls * CPAD + tid;
    if (tid < scf) {
      int pos = survLds[tid];
      cand[o] = ((u64)keyH[pos] << 32) | (u32)o; // low32 == global tie-order
      cbox[o] = sbox[pos];
    } else {
      cand[o] = ~0ULL;
    }
  }

  // ---- signal completion; last block does the global top-K ----
  __threadfence();                 // device-scope release of cand/cbox writes
  __syncthreads();
  if (tid == 0) lastSh = atomicAdd(done, 1u);
  __syncthreads();
  if (lastSh != NFG - 1) return;
  __threadfence();                 // acquire: see all blocks' cand/cbox

  u64* kk = (u64*)sbox;            // overlay (sbox no longer needed)
  if (tid == 0) cntLds = 0;
  __syncthreads();
  int np = 0;
  for (int t = tid; t < CTOT; t += NTHR) {
    u64 v = cand[t];
    kk[t] = v;
    np += (v != ~0ULL) ? 1 : 0;
  }
  atomicAdd(&cntLds, np);
  __syncthreads();
  const int M = cntLds;

  // exact global rank via 20 per-class binary searches (keys unique)
  for (int t = tid; t < CTOT; t += NTHR) {
    u64 kap = kk[t];
    if (kap == ~0ULL) continue;
    int rank = 0;
    #pragma unroll
    for (int c = 0; c < NFG; ++c) {
      const u64* a = kk + c * CPAD;
      int lb = 0;
      #pragma unroll
      for (int s2 = CPAD >> 1; s2; s2 >>= 1) {
        int p = lb + s2;
        if (a[p - 1] < kap) lb = p;
      }
      rank += lb;                  // count of keys < kap in class c
    }
    if (rank < K) {
      u32 flat = (u32)(kap & 0xFFFFFFFFu);
      float score = key_to_float((u32)(kap >> 32));
      int c2 = (int)(flat >> 7);   // / CPAD
      float4 b = cbox[flat];
      out[rank * 4 + 0] = b.x;
      out[rank * 4 + 1] = b.y;
      out[rank * 4 + 2] = b.z;
      out[rank * 4 + 3] = b.w;
      out[K * 4 + rank] = (float)(c2 + 1);
      out[K * 5 + rank] = score;
    }
  }
  for (int r = tid; r < K; r += NTHR) {
    if (r >= M) {
      out[r * 4 + 0] = 0.0f; out[r * 4 + 1] = 0.0f;
      out[r * 4 + 2] = 1.0f; out[r * 4 + 3] = 1.0f;
      out[K * 4 + r] = 0.0f;
      out[K * 5 + r] = 0.0f;
    }
  }
}

// ---- launch ---------------------------------------------------------------
extern "C" void kernel_launch(void* const* d_in, const int* in_sizes, int n_in,
                              void* d_out, int out_size, void* d_ws, size_t ws_size,
                              hipStream_t stream) {
  const float* rois        = (const float*)d_in[0];
  const float* locs        = (const float*)d_in[1];
  const float* scores      = (const float*)d_in[2];
  const float* min_score   = (const float*)d_in[3];
  const float* max_overlap = (const float*)d_in[4];
  const int*   top_k       = (const int*)d_in[5];

  char* ws = (char*)d_ws;
  // layout: cand 2560*8 | cbox 2560*16 | probsT 20*2048*4 | decoded 2048*16 | done 4
  u64*    cand    = (u64*)ws;
  float4* cbox    = (float4*)(ws + 20480);
  float*  probsT  = (float*)(ws + 20480 + 40960);
  float4* decoded = (float4*)(ws + 20480 + 40960 + 163840);
  u32*    done    = (u32*)(ws + 20480 + 40960 + 163840 + 32768);

  k_decode<<<NROI / DROWS, 256, 0, stream>>>(rois, locs, scores, probsT, decoded, done);
  k_nms<<<NFG, NTHR, 0, stream>>>(probsT, decoded, min_score, max_overlap,
                                  cand, cbox, done, (float*)d_out, top_k);
}

// Round 8
// 92.925 us; speedup vs baseline: 1.9539x; 1.1064x over previous
//
#include <hip/hip_runtime.h>
#include <cstdint>

#define NROI 2048
#define NCLS 21
#define NFG  20
#define CPAD 128          // survivor slots per class (>= top_k=100)
#define CTOT (NFG * CPAD) // 2560
#define NTHR 1024         // threads per NMS block (16 waves)
#define DROWS 256         // rows per decode block
#define RWIN 512          // NMS window: top-RWIN sorted rows get the bit matrix
#define CSEL 512          // contender cap for top-k rank-count

typedef unsigned long long u64;
typedef unsigned int u32;

// ---- sortable key helpers -------------------------------------------------
// desc_key(s): larger float -> smaller uint, so ascending sort on
// (keyH, keyL=index) == (score descending, index ascending).
__device__ __forceinline__ u32 desc_key(float s) {
  u32 u = __float_as_uint(s);
  u32 asc = (u & 0x80000000u) ? ~u : (u | 0x80000000u);
  return ~asc;
}
__device__ __forceinline__ float key_to_float(u32 desc) {
  u32 asc = ~desc;
  u32 u = (asc & 0x80000000u) ? (asc ^ 0x80000000u) : ~asc;
  return __uint_as_float(u);
}

// bitonic compare-exchange for element index i at pass (k, j):
// takeOther = lex(other<mine) XOR (amIlow != dir)
__device__ __forceinline__ void cmpex(u32& mh, u32& ml, u32 oh, u32 ol,
                                      int i, int j, int k) {
  bool amIlow = ((i & j) == 0);
  bool dir = ((i & k) == 0);
  bool otherLess = (oh < mh) || (oh == mh && ol < ml);
  if (otherLess != (amIlow != dir)) { mh = oh; ml = ol; }
}

// wave-0 parallel 256-bin bucket select: smallest bucket b with
// cum(h[0..b]) >= need; *outC = cum before b. (need >= 1, need <= total)
__device__ __forceinline__ void bucket_select(const int* h, int need, int lane,
                                              int* outB, int* outC) {
  int base = lane << 2;
  int c0 = h[base], c1 = h[base + 1], c2 = h[base + 2], c3 = h[base + 3];
  int s = c0 + c1 + c2 + c3;
  int pre = s;
  #pragma unroll
  for (int off = 1; off < 64; off <<= 1) {
    int v = __shfl_up(pre, off);
    if (lane >= off) pre += v;
  }
  u64 ball = __ballot(pre >= need);
  int ln = __ffsll((long long)ball) - 1;
  int exc = __shfl(pre, ln) - __shfl(s, ln);
  int b0 = __shfl(c0, ln), b1 = __shfl(c1, ln), b2 = __shfl(c2, ln);
  int bkt, cb;
  if (exc + b0 >= need)                { bkt = (ln << 2) + 0; cb = exc; }
  else if (exc + b0 + b1 >= need)      { bkt = (ln << 2) + 1; cb = exc + b0; }
  else if (exc + b0 + b1 + b2 >= need) { bkt = (ln << 2) + 2; cb = exc + b0 + b1; }
  else                                 { bkt = (ln << 2) + 3; cb = exc + b0 + b1 + b2; }
  if (lane == 0) { *outB = bkt; *outC = cb; }
}

// ---- phase 1: coalesced softmax + argmax + decode -------------------------
__global__ __launch_bounds__(256)
void k_decode(const float* __restrict__ rois,
              const float* __restrict__ locs,
              const float* __restrict__ scores,
              float* __restrict__ probsT,     // [NFG][NROI]: class c+1 -> row c
              float4* __restrict__ decoded,
              u32* __restrict__ done) {
  __shared__ float srow[DROWS][NCLS + 2];   // stride 23 (odd) -> conflict-free
  const int tid = threadIdx.x;
  const int rbase = blockIdx.x * DROWS;
  if (rbase == 0 && tid == 0) *done = 0u;   // reset last-block counter each launch

  const float* src = scores + (size_t)rbase * NCLS;
  for (int t = tid; t < DROWS * NCLS; t += 256)
    srow[t / NCLS][t % NCLS] = src[t];
  __syncthreads();

  const int r = rbase + tid;
  float s[NCLS];
  #pragma unroll
  for (int c = 0; c < NCLS; ++c) s[c] = srow[tid][c];
  float m = s[0];
  #pragma unroll
  for (int c = 0; c < NCLS; ++c) m = fmaxf(m, s[c]);
  float sum = 0.0f;
  #pragma unroll
  for (int c = 0; c < NCLS; ++c) { s[c] = expf(s[c] - m); sum += s[c]; }

  float pb = s[0] / sum; int best = 0;
  #pragma unroll
  for (int c = 1; c < NCLS; ++c) {
    float p = s[c] / sum;
    probsT[(c - 1) * NROI + r] = p;        // coalesced store per class
    if (p > pb) { pb = p; best = c; }      // strict > == first-index argmax
  }

  float4 roi = ((const float4*)rois)[r];
  float pcx = __fmul_rn(__fadd_rn(roi.x, roi.z), 0.5f);
  float pcy = __fmul_rn(__fadd_rn(roi.y, roi.w), 0.5f);
  float pw  = __fsub_rn(roi.z, roi.x);
  float ph  = __fsub_rn(roi.w, roi.y);

  float4 gl = ((const float4*)locs)[r * NCLS + best];   // 16B-aligned
  float g0 = gl.x / 10.0f;
  float g1 = gl.y / 10.0f;
  float g2 = gl.z / 20.0f;
  float g3 = gl.w / 20.0f;

  // no-FMA-contraction decode to match numpy rounding
  float cx = __fadd_rn(__fmul_rn(g0, pw), pcx);
  float cy = __fadd_rn(__fmul_rn(g1, ph), pcy);
  float w  = __fmul_rn(expf(g2), pw);
  float h  = __fmul_rn(expf(g3), ph);
  float hw = __fmul_rn(w, 0.5f);
  float hh = __fmul_rn(h, 0.5f);
  decoded[r] = make_float4(__fsub_rn(cx, hw), __fsub_rn(cy, hh),
                           __fadd_rn(cx, hw), __fadd_rn(cy, hh));
}

// ---- phase 2: per-class shfl-sort + bitmask NMS + last-block top-k --------
__global__ __launch_bounds__(NTHR)
void k_nms(const float* __restrict__ probsT,
           const float4* __restrict__ decoded,
           const float* __restrict__ min_score_p,
           const float* __restrict__ max_overlap_p,
           u64* __restrict__ cand,
           float4* __restrict__ cbox,
           u32* __restrict__ done,
           float* __restrict__ out,
           const int* __restrict__ top_k_p) {
  // LDS blob (u32 words), 56.5 KB + hist 2 KB:
  //  [0,2048)      keyH      (sorted keys, also sort mailbox A)
  //  [2048,4096)   keyL
  //  [4096,12288)  region C: sort mailbox B (first 16KB) -> 512x8 u64 mask
  //                -> tail kk[2560] + ckeys[512] overlay
  //  [12288,14336) boxes SoA bx0/by0/bx1/by1 [512] each
  //  [14336,14464) survRows[128]
  __shared__ u32 LDSW[14464];
  __shared__ int hist1[256], hist2[256];
  __shared__ int cntLds, scLds, rNextLds, killFlag, mSh, cCnt, selB1, selC1, selB2;
  __shared__ u32 lastSh;

  u32* keyH = LDSW;
  u32* keyL = LDSW + 2048;
  u32* mbH  = LDSW + 4096;
  u32* mbL  = LDSW + 6144;
  u64* maskW = (u64*)(LDSW + 4096);
  float* bx0 = (float*)(LDSW + 12288);
  float* by0 = (float*)(LDSW + 12800);
  float* bx1 = (float*)(LDSW + 13312);
  float* by1 = (float*)(LDSW + 13824);
  u32* survRows = LDSW + 14336;

  const int cls = blockIdx.x;
  const int tid = threadIdx.x;
  const int lane = tid & 63;
  const int wid = tid >> 6;
  const float msc = *min_score_p;
  const float ovr = *max_overlap_p;
  const int K = *top_k_p;
  const int Kcap = (K < CPAD) ? K : CPAD;

  if (tid == 0) { cntLds = 0; scLds = 0; rNextLds = RWIN; }
  __syncthreads();

  // ---- keys: thread owns elements tid and tid+1024 (registers) ----
  float p0v = probsT[cls * NROI + tid];
  float p1v = probsT[cls * NROI + tid + 1024];
  bool v0 = p0v > msc, v1 = p1v > msc;
  u32 h0 = desc_key(v0 ? p0v : -__builtin_inff());
  u32 l0 = (u32)tid;
  u32 h1 = desc_key(v1 ? p1v : -__builtin_inff());
  u32 l1 = (u32)(tid + 1024);
  {
    u64 ba = __ballot(v0), bb = __ballot(v1);
    if (lane == 0) atomicAdd(&cntLds, __popcll(ba) + __popcll(bb));
  }

  // ---- hybrid bitonic sort: shfl for j<=32, LDS mailbox for j in [64,512],
  //      in-thread for j=1024. 14 barriers total. ----
  int parity = 0;
  auto ldspass = [&](int k, int j) {
    u32* bH = parity ? keyH : mbH;
    u32* bL = parity ? keyL : mbL;
    parity ^= 1;
    bH[tid] = h0; bL[tid] = l0;
    bH[tid + 1024] = h1; bL[tid + 1024] = l1;
    __syncthreads();
    int p = tid ^ j;
    u32 oh = bH[p], ol = bL[p];
    cmpex(h0, l0, oh, ol, tid, j, k);
    oh = bH[p + 1024]; ol = bL[p + 1024];
    cmpex(h1, l1, oh, ol, tid + 1024, j, k);
  };
  auto shflpass = [&](int k, int j) {
    u32 oh = (u32)__shfl_xor((int)h0, j);
    u32 ol = (u32)__shfl_xor((int)l0, j);
    cmpex(h0, l0, oh, ol, tid, j, k);
    oh = (u32)__shfl_xor((int)h1, j);
    ol = (u32)__shfl_xor((int)l1, j);
    cmpex(h1, l1, oh, ol, tid + 1024, j, k);
  };

  for (int k = 2; k <= 64; k <<= 1)
    for (int j = k >> 1; j >= 1; j >>= 1) shflpass(k, j);
  for (int k = 128; k <= 1024; k <<= 1) {
    for (int j = k >> 1; j >= 64; j >>= 1) ldspass(k, j);
    for (int j = 32; j >= 1; j >>= 1) shflpass(k, j);
  }
  { // k = 2048: j=1024 is in-thread (ascending final merge)
    bool oLess = (h1 < h0) || (h1 == h0 && l1 < l0);
    if (oLess) { u32 th = h0, tl = l0; h0 = h1; l0 = l1; h1 = th; l1 = tl; }
    for (int j = 512; j >= 64; j >>= 1) ldspass(2048, j);
    for (int j = 32; j >= 1; j >>= 1) shflpass(2048, j);
  }
  __syncthreads();
  keyH[tid] = h0; keyL[tid] = l0;
  keyH[tid + 1024] = h1; keyL[tid + 1024] = l1;
  __syncthreads();

  const int nv = cntLds;

  // ---- gather top-RWIN boxes into SoA (conflict-free 4B lanes) ----
  if (tid < RWIN) {
    float4 b = decoded[keyL[tid]];
    bx0[tid] = b.x; by0[tid] = b.y; bx1[tid] = b.z; by1[tid] = b.w;
  }
  __syncthreads();

  // ---- build 512x512 suppression bit matrix (upper triangle chunks) ----
  // garbage stays only in words < (r>>6) of each row == rows already
  // processed when row r is swept -> harmless.
  for (int r = wid; r < RWIN; r += 16) {
    float ix0 = bx0[r], iy0 = by0[r], ix1 = bx1[r], iy1 = by1[r];
    float ia = __fmul_rn(__fsub_rn(ix1, ix0), __fsub_rn(iy1, iy0));
    for (int c = (r >> 6); c < 8; ++c) {
      int j = (c << 6) + lane;
      float jx0 = bx0[j], jy0 = by0[j], jx1 = bx1[j], jy1 = by1[j];
      float ab = __fmul_rn(__fsub_rn(jx1, jx0), __fsub_rn(jy1, jy0));
      float lx = fmaxf(ix0, jx0), ly = fmaxf(iy0, jy0);
      float rx = fminf(ix1, jx1), ry = fminf(iy1, jy1);
      float w_ = fmaxf(__fsub_rn(rx, lx), 0.0f);
      float h_ = fmaxf(__fsub_rn(ry, ly), 0.0f);
      float inter = __fmul_rn(w_, h_);
      float iou = __fdiv_rn(inter, __fsub_rn(__fadd_rn(ia, ab), inter));
      u64 bal = __ballot((iou > ovr) && (j > r));
      if (lane == 0) maskW[(r << 3) + c] = bal;
    }
  }
  __syncthreads();

  // ---- single-wave greedy sweep: shfl alive-check + OR, 4-deep prefetch ----
  if (wid == 0) {
    const int w8 = lane & 7;           // owned removed-word (lanes 8+ mirror)
    int start = nv - (w8 << 6);
    u64 rw = (start <= 0) ? ~0ULL : ((start >= 64) ? 0ULL : (~0ULL << start));
    int sc = 0;
    u64 a0 = maskW[(0 << 3) + w8], a1 = maskW[(1 << 3) + w8],
        a2 = maskW[(2 << 3) + w8], a3 = maskW[(3 << 3) + w8];
#define PROC(MM, RR)                                                         \
    {                                                                        \
      int r_ = (RR);                                                         \
      int src_ = r_ >> 6;                                                    \
      u32 wlo_ = (u32)__shfl((int)(u32)rw, src_);                            \
      u32 whi_ = (u32)__shfl((int)(u32)(rw >> 32), src_);                    \
      u64 wv_ = ((u64)whi_ << 32) | (u64)wlo_;                               \
      if (!((wv_ >> (r_ & 63)) & 1ULL)) {                                    \
        rw |= (MM);                                                          \
        if (lane == 0 && sc < CPAD) survRows[sc] = (u32)r_;                  \
        ++sc;                                                                \
      }                                                                      \
    }
    for (int base = 0; base < RWIN; base += 4) {
      int nb = base + 4;
      u64 b0 = 0, b1 = 0, b2 = 0, b3 = 0;
      if (nb < RWIN) {
        b0 = maskW[((nb + 0) << 3) + w8]; b1 = maskW[((nb + 1) << 3) + w8];
        b2 = maskW[((nb + 2) << 3) + w8]; b3 = maskW[((nb + 3) << 3) + w8];
      }
      PROC(a0, base + 0) PROC(a1, base + 1) PROC(a2, base + 2) PROC(a3, base + 3)
      if (sc >= Kcap) break;
      a0 = b0; a1 = b1; a2 = b2; a3 = b3;
    }
#undef PROC
    if (lane == 0) scLds = sc;
  }
  __syncthreads();

  // ---- exact fallback for rows beyond RWIN (expected never taken) ----
  while (true) {
    __syncthreads();
    int scN = scLds, rN = rNextLds;
    if (scN >= Kcap || rN >= nv) break;
    if (tid == 0) killFlag = 0;
    __syncthreads();
    float4 rb = decoded[keyL[rN]];
    bool kill = false;
    if (tid < scN) {
      int sr = (int)survRows[tid];
      float sx0_, sy0_, sx1_, sy1_;
      if (sr < RWIN) { sx0_ = bx0[sr]; sy0_ = by0[sr]; sx1_ = bx1[sr]; sy1_ = by1[sr]; }
      else { float4 sb = decoded[keyL[sr]]; sx0_ = sb.x; sy0_ = sb.y; sx1_ = sb.z; sy1_ = sb.w; }
      float ia = __fmul_rn(__fsub_rn(sx1_, sx0_), __fsub_rn(sy1_, sy0_));
      float ab = __fmul_rn(__fsub_rn(rb.z, rb.x), __fsub_rn(rb.w, rb.y));
      float lx = fmaxf(sx0_, rb.x), ly = fmaxf(sy0_, rb.y);
      float rx = fminf(sx1_, rb.z), ry = fminf(sy1_, rb.w);
      float w_ = fmaxf(__fsub_rn(rx, lx), 0.0f);
      float h_ = fmaxf(__fsub_rn(ry, ly), 0.0f);
      float inter = __fmul_rn(w_, h_);
      float iou = __fdiv_rn(inter, __fsub_rn(__fadd_rn(ia, ab), inter));
      kill = iou > ovr;
    }
    if (kill) atomicOr(&killFlag, 1);
    __syncthreads();
    if (tid == 0) {
      if (!killFlag) { survRows[scLds] = (u32)rN; scLds = scLds + 1; }
      rNextLds = rN + 1;
    }
  }
  __syncthreads();

  // ---- emit per-class survivor list (sorted order) ----
  int scf = scLds; if (scf > Kcap) scf = Kcap;
  if (tid < CPAD) {
    int o = cls * CPAD + tid;
    if (tid < scf) {
      int r = (int)survRows[tid];
      cand[o] = ((u64)keyH[r] << 32) | (u32)o;  // low32 == global tie-order
      float4 b;
      if (r < RWIN) b = make_float4(bx0[r], by0[r], bx1[r], by1[r]);
      else b = decoded[keyL[r]];
      cbox[o] = b;
    } else {
      cand[o] = ~0ULL;
    }
  }

  // ---- signal completion; last block does the global top-K ----
  __threadfence();
  __syncthreads();
  if (tid == 0) lastSh = atomicAdd(done, 1u);
  __syncthreads();
  if (lastSh != NFG - 1) return;
  __threadfence();

  u64* kk = maskW;            // overlay (mask dead)
  u64* ck = maskW + CTOT;     // contenders
  if (tid == 0) { cCnt = 0; }
  if (tid < 256) { hist1[tid] = 0; hist2[tid] = 0; }
  __syncthreads();
  for (int t = tid; t < CTOT; t += NTHR) {
    u64 v = cand[t];
    kk[t] = v;
    if (v != ~0ULL) atomicAdd(&hist1[(int)(v >> 56)], 1);
  }
  __syncthreads();
  if (wid == 0) {             // M = total valid count (wave reduce of hist1)
    int base = lane << 2;
    int s = hist1[base] + hist1[base + 1] + hist1[base + 2] + hist1[base + 3];
    #pragma unroll
    for (int off = 32; off; off >>= 1) s += __shfl_xor(s, off);
    if (lane == 0) mSh = s;
  }
  __syncthreads();
  const int M = mSh;
  const int Kneed = (K < M) ? K : M;

  if (Kneed > 0) {
    if (wid == 0) bucket_select(hist1, Kneed, lane, &selB1, &selC1);
    __syncthreads();
    const int B1 = selB1, C1 = selC1;
    for (int t = tid; t < CTOT; t += NTHR) {
      u64 v = kk[t];
      if (v != ~0ULL && (int)(v >> 56) == B1)
        atomicAdd(&hist2[(int)((v >> 48) & 255)], 1);
    }
    __syncthreads();
    if (wid == 0) bucket_select(hist2, Kneed - C1, lane, &selB2, &killFlag);
    __syncthreads();
    const int B2 = selB2;
    for (int t = tid; t < CTOT; t += NTHR) {   // compact contenders
      u64 v = kk[t];
      if (v == ~0ULL) continue;
      int b1 = (int)(v >> 56);
      int b2 = (int)((v >> 48) & 255);
      if (b1 < B1 || (b1 == B1 && b2 <= B2)) {
        int pos = atomicAdd(&cCnt, 1);
        if (pos < CSEL) ck[pos] = v;
      }
    }
    __syncthreads();
    const int C = cCnt;
    if (C <= CSEL) {
      // contender set downward-closed -> in-set rank == global rank
      if (tid < C) {
        u64 my = ck[tid];
        int rank = 0;
        for (int u = 0; u < C; ++u) rank += (ck[u] < my) ? 1 : 0;
        if (rank < K) {
          u32 flat = (u32)(my & 0xFFFFFFFFu);
          float score = key_to_float((u32)(my >> 32));
          int c2 = (int)(flat >> 7);
          float4 b = cbox[flat];
          out[rank * 4 + 0] = b.x;
          out[rank * 4 + 1] = b.y;
          out[rank * 4 + 2] = b.z;
          out[rank * 4 + 3] = b.w;
          out[K * 4 + rank] = (float)(c2 + 1);
          out[K * 5 + rank] = score;
        }
      }
    } else {
      // fallback: exact rank via 20 per-class binary searches
      for (int t = tid; t < CTOT; t += NTHR) {
        u64 kap = kk[t];
        if (kap == ~0ULL) continue;
        int rank = 0;
        #pragma unroll
        for (int cc2 = 0; cc2 < NFG; ++cc2) {
          const u64* a = kk + cc2 * CPAD;
          int lb = 0;
          #pragma unroll
          for (int s2 = CPAD >> 1; s2; s2 >>= 1) {
            int pq = lb + s2;
            if (a[pq - 1] < kap) lb = pq;
          }
          rank += lb;
        }
        if (rank < K) {
          u32 flat = (u32)(kap & 0xFFFFFFFFu);
          float score = key_to_float((u32)(kap >> 32));
          int c2 = (int)(flat >> 7);
          float4 b = cbox[flat];
          out[rank * 4 + 0] = b.x;
          out[rank * 4 + 1] = b.y;
          out[rank * 4 + 2] = b.z;
          out[rank * 4 + 3] = b.w;
          out[K * 4 + rank] = (float)(c2 + 1);
          out[K * 5 + rank] = score;
        }
      }
    }
  }
  __syncthreads();
  for (int r = tid; r < K; r += NTHR) {
    if (r >= M) {
      out[r * 4 + 0] = 0.0f; out[r * 4 + 1] = 0.0f;
      out[r * 4 + 2] = 1.0f; out[r * 4 + 3] = 1.0f;
      out[K * 4 + r] = 0.0f;
      out[K * 5 + r] = 0.0f;
    }
  }
}

// ---- launch ---------------------------------------------------------------
extern "C" void kernel_launch(void* const* d_in, const int* in_sizes, int n_in,
                              void* d_out, int out_size, void* d_ws, size_t ws_size,
                              hipStream_t stream) {
  const float* rois        = (const float*)d_in[0];
  const float* locs        = (const float*)d_in[1];
  const float* scores      = (const float*)d_in[2];
  const float* min_score   = (const float*)d_in[3];
  const float* max_overlap = (const float*)d_in[4];
  const int*   top_k       = (const int*)d_in[5];

  char* ws = (char*)d_ws;
  // layout: cand 2560*8 | cbox 2560*16 | probsT 20*2048*4 | decoded 2048*16 | done 4
  u64*    cand    = (u64*)ws;
  float4* cbox    = (float4*)(ws + 20480);
  float*  probsT  = (float*)(ws + 20480 + 40960);
  float4* decoded = (float4*)(ws + 20480 + 40960 + 163840);
  u32*    done    = (u32*)(ws + 20480 + 40960 + 163840 + 32768);

  k_decode<<<NROI / DROWS, 256, 0, stream>>>(rois, locs, scores, probsT, decoded, done);
  k_nms<<<NFG, NTHR, 0, stream>>>(probsT, decoded, min_score, max_overlap,
                                  cand, cbox, done, (float*)d_out, top_k);
}

// Round 9
// 78.695 us; speedup vs baseline: 2.3072x; 1.1808x over previous
//
#include <hip/hip_runtime.h>
#include <cstdint>

#define NROI 2048
#define NCLS 21
#define NFG  20
#define CPAD 128          // survivor slots per class (>= top_k=100)
#define CTOT (NFG * CPAD) // 2560
#define NTHR 1024         // threads per NMS block (16 waves)
#define SBLK 256          // rows per NMS stage
#define CSEL 512          // contender cap for top-k rank-count
#define DROWS 64          // rows per decode block

typedef unsigned long long u64;
typedef unsigned int u32;

// ---- sortable key helpers -------------------------------------------------
// desc_key(s): larger float -> smaller uint, so ascending sort on
// (keyH, keyL=index) == (score descending, index ascending).
__device__ __forceinline__ u32 desc_key(float s) {
  u32 u = __float_as_uint(s);
  u32 asc = (u & 0x80000000u) ? ~u : (u | 0x80000000u);
  return ~asc;
}
__device__ __forceinline__ float key_to_float(u32 desc) {
  u32 asc = ~desc;
  u32 u = (asc & 0x80000000u) ? (asc ^ 0x80000000u) : ~asc;
  return __uint_as_float(u);
}

// bitonic compare-exchange for element index i at pass (k, j)
__device__ __forceinline__ void cmpex(u32& mh, u32& ml, u32 oh, u32 ol,
                                      int i, int j, int k) {
  bool amIlow = ((i & j) == 0);
  bool dir = ((i & k) == 0);
  bool otherLess = (oh < mh) || (oh == mh && ol < ml);
  if (otherLess != (amIlow != dir)) { mh = oh; ml = ol; }
}

// wave-0 parallel 256-bin bucket select: smallest bucket b with
// cum(h[0..b]) >= need; *outC = cum before b. (1 <= need <= total)
__device__ __forceinline__ void bucket_select(const int* h, int need, int lane,
                                              int* outB, int* outC) {
  int base = lane << 2;
  int c0 = h[base], c1 = h[base + 1], c2 = h[base + 2], c3 = h[base + 3];
  int s = c0 + c1 + c2 + c3;
  int pre = s;
  #pragma unroll
  for (int off = 1; off < 64; off <<= 1) {
    int v = __shfl_up(pre, off);
    if (lane >= off) pre += v;
  }
  u64 ball = __ballot(pre >= need);
  int ln = __ffsll((long long)ball) - 1;
  int exc = __shfl(pre, ln) - __shfl(s, ln);
  int b0 = __shfl(c0, ln), b1 = __shfl(c1, ln), b2 = __shfl(c2, ln);
  int bkt, cb;
  if (exc + b0 >= need)                { bkt = (ln << 2) + 0; cb = exc; }
  else if (exc + b0 + b1 >= need)      { bkt = (ln << 2) + 1; cb = exc + b0; }
  else if (exc + b0 + b1 + b2 >= need) { bkt = (ln << 2) + 2; cb = exc + b0 + b1; }
  else                                 { bkt = (ln << 2) + 3; cb = exc + b0 + b1 + b2; }
  if (lane == 0) { *outB = bkt; *outC = cb; }
}

// ---- phase 1: coalesced softmax + argmax + decode (32 blocks x 64 thr) ----
__global__ __launch_bounds__(64)
void k_decode(const float* __restrict__ rois,
              const float* __restrict__ locs,
              const float* __restrict__ scores,
              float* __restrict__ probsT,     // [NFG][NROI]: class c+1 -> row c
              float4* __restrict__ decoded,
              u32* __restrict__ done) {
  __shared__ float srow[DROWS][NCLS + 2];   // stride 23 (odd) -> conflict-free
  const int tid = threadIdx.x;
  const int rbase = blockIdx.x * DROWS;
  if (rbase == 0 && tid == 0) *done = 0u;   // reset last-block counter each launch

  const float* src = scores + (size_t)rbase * NCLS;
  for (int t = tid; t < DROWS * NCLS; t += 64)
    srow[t / NCLS][t % NCLS] = src[t];
  __syncthreads();

  const int r = rbase + tid;
  float s[NCLS];
  #pragma unroll
  for (int c = 0; c < NCLS; ++c) s[c] = srow[tid][c];
  float m = s[0];
  #pragma unroll
  for (int c = 0; c < NCLS; ++c) m = fmaxf(m, s[c]);
  float sum = 0.0f;
  #pragma unroll
  for (int c = 0; c < NCLS; ++c) { s[c] = expf(s[c] - m); sum += s[c]; }

  float pb = s[0] / sum; int best = 0;
  #pragma unroll
  for (int c = 1; c < NCLS; ++c) {
    float p = s[c] / sum;
    probsT[(c - 1) * NROI + r] = p;        // coalesced store per class
    if (p > pb) { pb = p; best = c; }      // strict > == first-index argmax
  }

  float4 roi = ((const float4*)rois)[r];
  float pcx = __fmul_rn(__fadd_rn(roi.x, roi.z), 0.5f);
  float pcy = __fmul_rn(__fadd_rn(roi.y, roi.w), 0.5f);
  float pw  = __fsub_rn(roi.z, roi.x);
  float ph  = __fsub_rn(roi.w, roi.y);

  float4 gl = ((const float4*)locs)[r * NCLS + best];   // 16B-aligned
  float g0 = gl.x / 10.0f;
  float g1 = gl.y / 10.0f;
  float g2 = gl.z / 20.0f;
  float g3 = gl.w / 20.0f;

  // no-FMA-contraction decode to match numpy rounding
  float cx = __fadd_rn(__fmul_rn(g0, pw), pcx);
  float cy = __fadd_rn(__fmul_rn(g1, ph), pcy);
  float w  = __fmul_rn(expf(g2), pw);
  float h  = __fmul_rn(expf(g3), ph);
  float hw = __fmul_rn(w, 0.5f);
  float hh = __fmul_rn(h, 0.5f);
  decoded[r] = make_float4(__fsub_rn(cx, hw), __fsub_rn(cy, hh),
                           __fadd_rn(cx, hw), __fadd_rn(cy, hh));
}

// ---- phase 2: per-class shfl-sort + staged bitmask NMS + last-block top-k -
__global__ __launch_bounds__(NTHR)
void k_nms(const float* __restrict__ probsT,
           const float4* __restrict__ decoded,
           const float* __restrict__ min_score_p,
           const float* __restrict__ max_overlap_p,
           u64* __restrict__ cand,
           float4* __restrict__ cbox,
           u32* __restrict__ done,
           float* __restrict__ out,
           const int* __restrict__ top_k_p) {
  // LDS blob (u32 words), 32 KB:
  //  [0,2048)      keyH            (tail overlay: kk[2560] u64 @0..5120)
  //  [2048,4096)   keyL
  //  [4096,8192)   sort mailbox (mbH@4096, mbL@6144); after sort:
  //    maskW u64[256*4]  @4096..6144
  //    stage SoA bx0/by0/bx1/by1/area[256] @6144..7424
  //    surv SoA sx0/sy0/sx1/sy1/sarea[128] @7424..8064
  //    survRows[128] @8064..8192
  //    (tail ck u64[512] @5120..6144)
  __shared__ u32 LDSW[8192];
  __shared__ u64 remInit[4];
  __shared__ int hist1[256], hist2[256];
  __shared__ int cntLds, scLds, mSh, cCnt, selB1, selC1, selB2, selDummy;
  __shared__ u32 lastSh;

  u32* keyH = LDSW;
  u32* keyL = LDSW + 2048;
  u32* mbH  = LDSW + 4096;
  u32* mbL  = LDSW + 6144;
  u64* maskW = (u64*)(LDSW + 4096);
  float* bx0 = (float*)(LDSW + 6144);
  float* by0 = (float*)(LDSW + 6400);
  float* bx1 = (float*)(LDSW + 6656);
  float* by1 = (float*)(LDSW + 6912);
  float* areaA = (float*)(LDSW + 7168);
  float* sx0 = (float*)(LDSW + 7424);
  float* sy0 = (float*)(LDSW + 7552);
  float* sx1 = (float*)(LDSW + 7680);
  float* sy1 = (float*)(LDSW + 7808);
  float* sarea = (float*)(LDSW + 7936);
  u32* survRows = LDSW + 8064;

  const int cls = blockIdx.x;
  const int tid = threadIdx.x;
  const int lane = tid & 63;
  const int wid = tid >> 6;
  const float msc = *min_score_p;
  const float ovr = *max_overlap_p;
  const int K = *top_k_p;
  const int Kcap = (K < CPAD) ? K : CPAD;

  if (tid == 0) { cntLds = 0; scLds = 0; }
  if (tid < 4) remInit[tid] = 0ULL;
  __syncthreads();

  // ---- keys: thread owns elements tid and tid+1024 (registers) ----
  float p0v = probsT[cls * NROI + tid];
  float p1v = probsT[cls * NROI + tid + 1024];
  bool v0 = p0v > msc, v1 = p1v > msc;
  u32 h0 = desc_key(v0 ? p0v : -__builtin_inff());
  u32 l0 = (u32)tid;
  u32 h1 = desc_key(v1 ? p1v : -__builtin_inff());
  u32 l1 = (u32)(tid + 1024);
  {
    u64 ba = __ballot(v0), bb = __ballot(v1);
    if (lane == 0) atomicAdd(&cntLds, __popcll(ba) + __popcll(bb));
  }

  // ---- hybrid bitonic sort (14 LDS passes + shfl passes) ----
  int parity = 0;
  auto ldspass = [&](int k, int j) {
    u32* bH = parity ? keyH : mbH;
    u32* bL = parity ? keyL : mbL;
    parity ^= 1;
    bH[tid] = h0; bL[tid] = l0;
    bH[tid + 1024] = h1; bL[tid + 1024] = l1;
    __syncthreads();
    int p = tid ^ j;
    u32 oh = bH[p], ol = bL[p];
    cmpex(h0, l0, oh, ol, tid, j, k);
    oh = bH[p + 1024]; ol = bL[p + 1024];
    cmpex(h1, l1, oh, ol, tid + 1024, j, k);
  };
  auto shflpass = [&](int k, int j) {
    u32 oh = (u32)__shfl_xor((int)h0, j);
    u32 ol = (u32)__shfl_xor((int)l0, j);
    cmpex(h0, l0, oh, ol, tid, j, k);
    oh = (u32)__shfl_xor((int)h1, j);
    ol = (u32)__shfl_xor((int)l1, j);
    cmpex(h1, l1, oh, ol, tid + 1024, j, k);
  };

  for (int k = 2; k <= 64; k <<= 1)
    for (int j = k >> 1; j >= 1; j >>= 1) shflpass(k, j);
  for (int k = 128; k <= 1024; k <<= 1) {
    for (int j = k >> 1; j >= 64; j >>= 1) ldspass(k, j);
    for (int j = 32; j >= 1; j >>= 1) shflpass(k, j);
  }
  { // k = 2048: j=1024 is in-thread (ascending final merge)
    bool oLess = (h1 < h0) || (h1 == h0 && l1 < l0);
    if (oLess) { u32 th = h0, tl = l0; h0 = h1; l0 = l1; h1 = th; l1 = tl; }
    for (int j = 512; j >= 64; j >>= 1) ldspass(2048, j);
    for (int j = 32; j >= 1; j >>= 1) shflpass(2048, j);
  }
  __syncthreads();
  keyH[tid] = h0; keyL[tid] = l0;
  keyH[tid + 1024] = h1; keyL[tid + 1024] = l1;
  __syncthreads();

  const int nv = cntLds;
  int sc = 0;

  // ---- staged greedy NMS: 256 sorted rows per stage ----
  for (int base = 0; base < nv && sc < Kcap; base += SBLK) {
    // gather stage boxes into SoA (+ areas)
    if (tid < SBLK) {
      int r = base + tid; if (r > NROI - 1) r = NROI - 1;   // clamp (dead rows)
      float4 b = decoded[keyL[r]];
      bx0[tid] = b.x; by0[tid] = b.y; bx1[tid] = b.z; by1[tid] = b.w;
      areaA[tid] = __fmul_rn(__fsub_rn(b.z, b.x), __fsub_rn(b.w, b.y));
    }
    __syncthreads();

    // column-kill: suppress this stage's cols by ALL previous survivors
    if (base > 0 && tid < SBLK) {
      float jx0 = bx0[tid], jy0 = by0[tid], jx1 = bx1[tid], jy1 = by1[tid];
      float ab = areaA[tid];
      bool kill = false;
      for (int u = 0; u < sc; ++u) {
        float ix0 = sx0[u], iy0 = sy0[u], ix1 = sx1[u], iy1 = sy1[u]; // broadcast
        float ia = sarea[u];
        float lx = fmaxf(ix0, jx0), ly = fmaxf(iy0, jy0);
        float rx = fminf(ix1, jx1), ry = fminf(iy1, jy1);
        float w_ = fmaxf(__fsub_rn(rx, lx), 0.0f);
        float h_ = fmaxf(__fsub_rn(ry, ly), 0.0f);
        float inter = __fmul_rn(w_, h_);
        float iou = __fdiv_rn(inter, __fsub_rn(__fadd_rn(ia, ab), inter));
        kill = kill || (iou > ovr);
      }
      u64 bal = __ballot(kill);
      if (lane == 0) remInit[wid] = bal;
    }

    // build 256x256 upper-triangle suppression bit matrix (16 waves)
    for (int r2 = wid; r2 < SBLK; r2 += 16) {
      float ix0 = bx0[r2], iy0 = by0[r2], ix1 = bx1[r2], iy1 = by1[r2];
      float ia = areaA[r2];
      for (int ct = (r2 >> 6); ct < 4; ++ct) {
        int j = (ct << 6) + lane;
        float jx0 = bx0[j], jy0 = by0[j], jx1 = bx1[j], jy1 = by1[j];
        float ab = areaA[j];
        float lx = fmaxf(ix0, jx0), ly = fmaxf(iy0, jy0);
        float rx = fminf(ix1, jx1), ry = fminf(iy1, jy1);
        float w_ = fmaxf(__fsub_rn(rx, lx), 0.0f);
        float h_ = fmaxf(__fsub_rn(ry, ly), 0.0f);
        float inter = __fmul_rn(w_, h_);
        float iou = __fdiv_rn(inter, __fsub_rn(__fadd_rn(ia, ab), inter));
        bool bit = iou > ovr;
        if (ct == (r2 >> 6)) bit = bit && (j > r2);
        u64 bal = __ballot(bit);
        if (lane == 0) maskW[(r2 << 2) + ct] = bal;
      }
    }
    __syncthreads();

    // ---- sweep (wave 0, all lanes replicated; broadcast LDS reads) ----
    if (wid == 0) {
      int t0 = nv - base;
      u64 rw0 = (t0 <= 0) ? ~0ULL : ((t0 >= 64) ? 0ULL : (~0ULL << t0));
      int t1 = t0 - 64;
      u64 rw1 = (t1 <= 0) ? ~0ULL : ((t1 >= 64) ? 0ULL : (~0ULL << t1));
      int t2 = t0 - 128;
      u64 rw2 = (t2 <= 0) ? ~0ULL : ((t2 >= 64) ? 0ULL : (~0ULL << t2));
      int t3 = t0 - 192;
      u64 rw3 = (t3 <= 0) ? ~0ULL : ((t3 >= 64) ? 0ULL : (~0ULL << t3));
      rw0 |= remInit[0]; rw1 |= remInit[1]; rw2 |= remInit[2]; rw3 |= remInit[3];

      int scW = sc;
      bool full = false;
      int r = 0;
      u64 mA0 = maskW[0], mA1 = maskW[1], mA2 = maskW[2], mA3 = maskW[3];
#define SWEEPW(RW)                                                            \
      for (int b = 0; b < 64 && !full; ++b, ++r) {                            \
        u64 n0 = 0, n1 = 0, n2 = 0, n3 = 0;                                   \
        if (r + 1 < SBLK) {                                                   \
          n0 = maskW[((r + 1) << 2) + 0]; n1 = maskW[((r + 1) << 2) + 1];     \
          n2 = maskW[((r + 1) << 2) + 2]; n3 = maskW[((r + 1) << 2) + 3];     \
        }                                                                     \
        if (!((RW >> b) & 1ULL)) {                                            \
          rw0 |= mA0; rw1 |= mA1; rw2 |= mA2; rw3 |= mA3;                     \
          if (lane == 0) {                                                    \
            survRows[scW] = (u32)(base + r);                                  \
            sx0[scW] = bx0[r]; sy0[scW] = by0[r];                             \
            sx1[scW] = bx1[r]; sy1[scW] = by1[r];                             \
            sarea[scW] = areaA[r];                                            \
          }                                                                   \
          ++scW;                                                              \
          if (scW >= Kcap) full = true;                                       \
        }                                                                     \
        mA0 = n0; mA1 = n1; mA2 = n2; mA3 = n3;                               \
      }
      SWEEPW(rw0) SWEEPW(rw1) SWEEPW(rw2) SWEEPW(rw3)
#undef SWEEPW
      if (lane == 0) scLds = scW;
    }
    __syncthreads();
    sc = scLds;
  }
  __syncthreads();

  // ---- emit per-class survivor list (sorted order) ----
  if (tid < CPAD) {
    int o = cls * CPAD + tid;
    if (tid < sc) {
      int r = (int)survRows[tid];
      cand[o] = ((u64)keyH[r] << 32) | (u32)o;  // low32 == global tie-order
      cbox[o] = make_float4(sx0[tid], sy0[tid], sx1[tid], sy1[tid]);
    } else {
      cand[o] = ~0ULL;
    }
  }

  // ---- signal completion; last block does the global top-K ----
  __threadfence();
  __syncthreads();
  if (tid == 0) lastSh = atomicAdd(done, 1u);
  __syncthreads();
  if (lastSh != NFG - 1) return;
  __threadfence();

  u64* kk = (u64*)LDSW;            // overlay keyH/keyL (dead)
  u64* ck = (u64*)(LDSW + 5120);   // contenders
  if (tid == 0) { cCnt = 0; }
  if (tid < 256) { hist1[tid] = 0; hist2[tid] = 0; }
  __syncthreads();
  for (int t = tid; t < CTOT; t += NTHR) {
    u64 v = cand[t];
    kk[t] = v;
    if (v != ~0ULL) atomicAdd(&hist1[(int)(v >> 56)], 1);
  }
  __syncthreads();
  if (wid == 0) {                  // M = total valid count (wave reduce)
    int b4 = lane << 2;
    int s = hist1[b4] + hist1[b4 + 1] + hist1[b4 + 2] + hist1[b4 + 3];
    #pragma unroll
    for (int off = 32; off; off >>= 1) s += __shfl_xor(s, off);
    if (lane == 0) mSh = s;
  }
  __syncthreads();
  const int M = mSh;
  const int Kneed = (K < M) ? K : M;

  if (Kneed > 0) {
    if (wid == 0) bucket_select(hist1, Kneed, lane, &selB1, &selC1);
    __syncthreads();
    const int B1 = selB1, C1 = selC1;
    for (int t = tid; t < CTOT; t += NTHR) {
      u64 v = kk[t];
      if (v != ~0ULL && (int)(v >> 56) == B1)
        atomicAdd(&hist2[(int)((v >> 48) & 255)], 1);
    }
    __syncthreads();
    if (wid == 0) bucket_select(hist2, Kneed - C1, lane, &selB2, &selDummy);
    __syncthreads();
    const int B2 = selB2;
    for (int t = tid; t < CTOT; t += NTHR) {   // compact contenders
      u64 v = kk[t];
      if (v == ~0ULL) continue;
      int b1 = (int)(v >> 56);
      int b2 = (int)((v >> 48) & 255);
      if (b1 < B1 || (b1 == B1 && b2 <= B2)) {
        int pos = atomicAdd(&cCnt, 1);
        if (pos < CSEL) ck[pos] = v;
      }
    }
    __syncthreads();
    const int C = cCnt;
    if (C <= CSEL) {
      // contender set downward-closed -> in-set rank == global rank
      if (tid < C) {
        u64 my = ck[tid];
        int rank = 0;
        for (int u = 0; u < C; ++u) rank += (ck[u] < my) ? 1 : 0;
        if (rank < K) {
          u32 flat = (u32)(my & 0xFFFFFFFFu);
          float score = key_to_float((u32)(my >> 32));
          int c2 = (int)(flat >> 7);
          float4 b = cbox[flat];
          out[rank * 4 + 0] = b.x;
          out[rank * 4 + 1] = b.y;
          out[rank * 4 + 2] = b.z;
          out[rank * 4 + 3] = b.w;
          out[K * 4 + rank] = (float)(c2 + 1);
          out[K * 5 + rank] = score;
        }
      }
    } else {
      // fallback: exact rank via 20 per-class binary searches
      for (int t = tid; t < CTOT; t += NTHR) {
        u64 kap = kk[t];
        if (kap == ~0ULL) continue;
        int rank = 0;
        #pragma unroll
        for (int cc2 = 0; cc2 < NFG; ++cc2) {
          const u64* a = kk + cc2 * CPAD;
          int lb = 0;
          #pragma unroll
          for (int s2 = CPAD >> 1; s2; s2 >>= 1) {
            int pq = lb + s2;
            if (a[pq - 1] < kap) lb = pq;
          }
          rank += lb;
        }
        if (rank < K) {
          u32 flat = (u32)(kap & 0xFFFFFFFFu);
          float score = key_to_float((u32)(kap >> 32));
          int c2 = (int)(flat >> 7);
          float4 b = cbox[flat];
          out[rank * 4 + 0] = b.x;
          out[rank * 4 + 1] = b.y;
          out[rank * 4 + 2] = b.z;
          out[rank * 4 + 3] = b.w;
          out[K * 4 + rank] = (float)(c2 + 1);
          out[K * 5 + rank] = score;
        }
      }
    }
  }
  __syncthreads();
  for (int r = tid; r < K; r += NTHR) {
    if (r >= M) {
      out[r * 4 + 0] = 0.0f; out[r * 4 + 1] = 0.0f;
      out[r * 4 + 2] = 1.0f; out[r * 4 + 3] = 1.0f;
      out[K * 4 + r] = 0.0f;
      out[K * 5 + r] = 0.0f;
    }
  }
}

// ---- launch ---------------------------------------------------------------
extern "C" void kernel_launch(void* const* d_in, const int* in_sizes, int n_in,
                              void* d_out, int out_size, void* d_ws, size_t ws_size,
                              hipStream_t stream) {
  const float* rois        = (const float*)d_in[0];
  const float* locs        = (const float*)d_in[1];
  const float* scores      = (const float*)d_in[2];
  const float* min_score   = (const float*)d_in[3];
  const float* max_overlap = (const float*)d_in[4];
  const int*   top_k       = (const int*)d_in[5];

  char* ws = (char*)d_ws;
  // layout: cand 2560*8 | cbox 2560*16 | probsT 20*2048*4 | decoded 2048*16 | done 4
  u64*    cand    = (u64*)ws;
  float4* cbox    = (float4*)(ws + 20480);
  float*  probsT  = (float*)(ws + 20480 + 40960);
  float4* decoded = (float4*)(ws + 20480 + 40960 + 163840);
  u32*    done    = (u32*)(ws + 20480 + 40960 + 163840 + 32768);

  k_decode<<<NROI / DROWS, 64, 0, stream>>>(rois, locs, scores, probsT, decoded, done);
  k_nms<<<NFG, NTHR, 0, stream>>>(probsT, decoded, min_score, max_overlap,
                                  cand, cbox, done, (float*)d_out, top_k);
}

// Round 10
// 69.027 us; speedup vs baseline: 2.6304x; 1.1401x over previous
//
#include <hip/hip_runtime.h>
#include <cstdint>

#define NROI 2048
#define NCLS 21
#define NFG  20
#define CPAD 128          // survivor slots per class (>= top_k=100)
#define CTOT (NFG * CPAD) // 2560
#define NTHR 1024         // threads per NMS block (16 waves)
#define SBLK 256          // rows per NMS stage
#define RSEL 384          // selection rank target per window
#define SCAP 512          // selection capacity (sorted window size)
#define CSEL 512          // contender cap for top-k rank-count
#define DROWS 64          // rows per decode block
#define INVH 0xFF800000u  // desc_key(-inf) == invalid marker

typedef unsigned long long u64;
typedef unsigned int u32;

// ---- sortable key helpers -------------------------------------------------
// desc_key(s): larger float -> smaller uint, so ascending sort on
// u64 key = (desc_key(score)<<32)|index == (score desc, index asc).
__device__ __forceinline__ u32 desc_key(float s) {
  u32 u = __float_as_uint(s);
  u32 asc = (u & 0x80000000u) ? ~u : (u | 0x80000000u);
  return ~asc;
}
__device__ __forceinline__ float key_to_float(u32 desc) {
  u32 asc = ~desc;
  u32 u = (asc & 0x80000000u) ? (asc ^ 0x80000000u) : ~asc;
  return __uint_as_float(u);
}
__device__ __forceinline__ u64 shflx_u64(u64 v, int m) {
  u32 lo = (u32)v, hi = (u32)(v >> 32);
  lo = (u32)__shfl_xor((int)lo, m);
  hi = (u32)__shfl_xor((int)hi, m);
  return ((u64)hi << 32) | (u64)lo;
}
// bitonic compare-exchange for element i at pass (k, j), u64 lex order
__device__ __forceinline__ void cmpex64(u64& mine, u64 other, int i, int j, int k) {
  bool amIlow = ((i & j) == 0);
  bool dir = ((i & k) == 0);
  bool otherLess = other < mine;
  if (otherLess != (amIlow != dir)) mine = other;
}

// wave-0 parallel 256-bin bucket select: smallest bucket b with
// cum(h[0..b]) >= need; *outC = cum before b. (1 <= need <= total)
__device__ __forceinline__ void bucket_select(const int* h, int need, int lane,
                                              int* outB, int* outC) {
  int base = lane << 2;
  int c0 = h[base], c1 = h[base + 1], c2 = h[base + 2], c3 = h[base + 3];
  int s = c0 + c1 + c2 + c3;
  int pre = s;
  #pragma unroll
  for (int off = 1; off < 64; off <<= 1) {
    int v = __shfl_up(pre, off);
    if (lane >= off) pre += v;
  }
  u64 ball = __ballot(pre >= need);
  int ln = __ffsll((long long)ball) - 1;
  int exc = __shfl(pre, ln) - __shfl(s, ln);
  int b0 = __shfl(c0, ln), b1 = __shfl(c1, ln), b2 = __shfl(c2, ln);
  int bkt, cb;
  if (exc + b0 >= need)                { bkt = (ln << 2) + 0; cb = exc; }
  else if (exc + b0 + b1 >= need)      { bkt = (ln << 2) + 1; cb = exc + b0; }
  else if (exc + b0 + b1 + b2 >= need) { bkt = (ln << 2) + 2; cb = exc + b0 + b1; }
  else                                 { bkt = (ln << 2) + 3; cb = exc + b0 + b1 + b2; }
  if (lane == 0) { *outB = bkt; *outC = cb; }
}

// ---- phase 1: coalesced softmax + argmax + decode (32 blocks x 64 thr) ----
__global__ __launch_bounds__(64)
void k_decode(const float* __restrict__ rois,
              const float* __restrict__ locs,
              const float* __restrict__ scores,
              float* __restrict__ probsT,     // [NFG][NROI]: class c+1 -> row c
              float4* __restrict__ decoded,
              u32* __restrict__ done) {
  __shared__ float srow[DROWS][NCLS + 2];   // stride 23 (odd) -> conflict-free
  const int tid = threadIdx.x;
  const int rbase = blockIdx.x * DROWS;
  if (rbase == 0 && tid == 0) *done = 0u;   // reset last-block counter each launch

  const float* src = scores + (size_t)rbase * NCLS;
  for (int t = tid; t < DROWS * NCLS; t += 64)
    srow[t / NCLS][t % NCLS] = src[t];
  __syncthreads();

  const int r = rbase + tid;
  float s[NCLS];
  #pragma unroll
  for (int c = 0; c < NCLS; ++c) s[c] = srow[tid][c];
  float m = s[0];
  #pragma unroll
  for (int c = 0; c < NCLS; ++c) m = fmaxf(m, s[c]);
  float sum = 0.0f;
  #pragma unroll
  for (int c = 0; c < NCLS; ++c) { s[c] = expf(s[c] - m); sum += s[c]; }

  float pb = s[0] / sum; int best = 0;
  #pragma unroll
  for (int c = 1; c < NCLS; ++c) {
    float p = s[c] / sum;
    probsT[(c - 1) * NROI + r] = p;        // coalesced store per class
    if (p > pb) { pb = p; best = c; }      // strict > == first-index argmax
  }

  float4 roi = ((const float4*)rois)[r];
  float pcx = __fmul_rn(__fadd_rn(roi.x, roi.z), 0.5f);
  float pcy = __fmul_rn(__fadd_rn(roi.y, roi.w), 0.5f);
  float pw  = __fsub_rn(roi.z, roi.x);
  float ph  = __fsub_rn(roi.w, roi.y);

  float4 gl = ((const float4*)locs)[r * NCLS + best];   // 16B-aligned
  float g0 = gl.x / 10.0f;
  float g1 = gl.y / 10.0f;
  float g2 = gl.z / 20.0f;
  float g3 = gl.w / 20.0f;

  // no-FMA-contraction decode to match numpy rounding
  float cx = __fadd_rn(__fmul_rn(g0, pw), pcx);
  float cy = __fadd_rn(__fmul_rn(g1, ph), pcy);
  float w  = __fmul_rn(expf(g2), pw);
  float h  = __fmul_rn(expf(g3), ph);
  float hw = __fmul_rn(w, 0.5f);
  float hh = __fmul_rn(h, 0.5f);
  decoded[r] = make_float4(__fsub_rn(cx, hw), __fsub_rn(cy, hh),
                           __fadd_rn(cx, hw), __fadd_rn(cy, hh));
}

// ---- phase 2: select+sort window -> staged bitmask NMS -> last-block topk -
__global__ __launch_bounds__(NTHR)
void k_nms(const float* __restrict__ probsT,
           const float4* __restrict__ decoded,
           const float* __restrict__ min_score_p,
           const float* __restrict__ max_overlap_p,
           u64* __restrict__ cand,
           float4* __restrict__ cbox,
           u32* __restrict__ done,
           float* __restrict__ out,
           const int* __restrict__ top_k_p) {
  // LDS word map (u32), 28 KB total:
  //  [0,1024)     mbA u64[512]        (sort mailbox A; tail: kk[0..])
  //  [1024,2048)  mbB u64[512]        (sort mailbox B)
  //  [2048,3072)  skeyW u64[512]      (sorted window keys)
  //  [3072,5120)  maskW u64[256*4]
  //  [5120,6400)  stage SoA bx0/by0/bx1/by1/areaA [256] each   (tail: ck@5120)
  //  [6400,7040)  surv SoA sx0/sy0/sx1/sy1/sarea [128] each
  //  [7040,7168)  survKeyH[128]
  __shared__ u32 LDSW[7168];
  __shared__ u64 remInitW[4];
  __shared__ int hist1[256], hist2[256];
  __shared__ int cntLds, scLds, cSelSh, selB1, selC1, selB2, selD2, mSh, cCnt;
  __shared__ u32 lastSh;

  u64* mbAu    = (u64*)(LDSW + 0);
  u64* mbBu    = (u64*)(LDSW + 1024);
  u64* skeyW64 = (u64*)(LDSW + 2048);
  u64* maskW   = (u64*)(LDSW + 3072);
  float* bx0   = (float*)(LDSW + 5120);
  float* by0   = (float*)(LDSW + 5376);
  float* bx1   = (float*)(LDSW + 5632);
  float* by1   = (float*)(LDSW + 5888);
  float* areaA = (float*)(LDSW + 6144);
  float* sx0   = (float*)(LDSW + 6400);
  float* sy0   = (float*)(LDSW + 6528);
  float* sx1   = (float*)(LDSW + 6656);
  float* sy1   = (float*)(LDSW + 6784);
  float* sarea = (float*)(LDSW + 6912);
  u32* survKeyH = LDSW + 7040;

  const int cls = blockIdx.x;
  const int tid = threadIdx.x;
  const int lane = tid & 63;
  const int wid = tid >> 6;
  const float msc = *min_score_p;
  const float ovr = *max_overlap_p;
  const int K = *top_k_p;
  const int Kcap = (K < CPAD) ? K : CPAD;

  if (tid == 0) { cntLds = 0; scLds = 0; }
  __syncthreads();

  // ---- per-thread keys (2 rows each) + valid count ----
  float p0v = probsT[cls * NROI + tid];
  float p1v = probsT[cls * NROI + tid + 1024];
  bool v0 = p0v > msc, v1 = p1v > msc;
  u64 kq0 = ((u64)desc_key(v0 ? p0v : -__builtin_inff()) << 32) | (u32)tid;
  u64 kq1 = ((u64)desc_key(v1 ? p1v : -__builtin_inff()) << 32) | (u32)(tid + 1024);
  {
    u64 ba = __ballot(v0), bb = __ballot(v1);
    if (lane == 0) atomicAdd(&cntLds, __popcll(ba) + __popcll(bb));
  }
  __syncthreads();
  const int nv = cntLds;

  int sc = 0;
  int processed = 0;
  u64 minKey = 0ULL;   // exclusive lower bound of already-processed keys

  // ================= selection-window loop (1 window typical) =============
  while (sc < Kcap && processed < nv) {
    int rem = nv - processed;
    int need = (rem < RSEL) ? rem : RSEL;

    // ---- 2-level histogram threshold select (exact, prefix-closed) ----
    if (tid < 256) { hist1[tid] = 0; hist2[tid] = 0; }
    if (tid == 0) cSelSh = 0;
    __syncthreads();
    bool val0 = (kq0 > minKey) && ((u32)(kq0 >> 32) < INVH);
    bool val1 = (kq1 > minKey) && ((u32)(kq1 >> 32) < INVH);
    if (val0) atomicAdd(&hist1[(int)((kq0 >> 56) & 255)], 1);
    if (val1) atomicAdd(&hist1[(int)((kq1 >> 56) & 255)], 1);
    __syncthreads();
    if (wid == 0) bucket_select(hist1, need, lane, &selB1, &selC1);
    __syncthreads();
    const int B1 = selB1, C1 = selC1;
    if (val0 && (int)((kq0 >> 56) & 255) == B1)
      atomicAdd(&hist2[(int)((kq0 >> 48) & 255)], 1);
    if (val1 && (int)((kq1 >> 56) & 255) == B1)
      atomicAdd(&hist2[(int)((kq1 >> 48) & 255)], 1);
    __syncthreads();
    if (wid == 0) bucket_select(hist2, need - C1, lane, &selB2, &selD2);
    __syncthreads();
    const int pred16 = (selB1 << 8) | selB2;

    // ---- compact selected keys (order irrelevant; sorted next) ----
    bool s0 = val0 && (int)((kq0 >> 48) & 0xFFFF) <= pred16;
    bool s1 = val1 && (int)((kq1 >> 48) & 0xFFFF) <= pred16;
    {
      u64 b0 = __ballot(s0), b1 = __ballot(s1);
      int cnt = __popcll(b0) + __popcll(b1);
      int basePos = 0;
      if (lane == 0) basePos = cnt ? atomicAdd(&cSelSh, cnt) : 0;
      basePos = __shfl(basePos, 0);
      u64 lm = (lane == 63) ? ~0ULL >> 1 : ((1ULL << lane) - 1ULL);
      lm = (1ULL << lane) - 1ULL;   // lane<64: safe (1ULL<<63 ok)
      int p0 = basePos + __popcll(b0 & lm);
      int p1 = basePos + __popcll(b0) + __popcll(b1 & lm);
      if (s0 && p0 < SCAP) mbAu[p0] = kq0;
      if (s1 && p1 < SCAP) mbAu[p1] = kq1;
    }
    __syncthreads();
    int Csel = cSelSh; if (Csel > SCAP) Csel = SCAP;  // clamp (float-continuous
                                                      // scores: never overflows)
    if (tid < SCAP && tid >= Csel) mbAu[tid] = ~0ULL;
    __syncthreads();

    // ---- bitonic sort 512 (threads<512 hold 1 element; pad sorts last) ----
    u64 key = (tid < SCAP) ? mbAu[tid] : ~0ULL;
    int parity = 0;
    auto ldsp = [&](int k, int j) {
      u64* buf = parity ? mbBu : mbAu; parity ^= 1;
      if (tid < SCAP) buf[tid] = key;
      __syncthreads();
      if (tid < SCAP) { u64 o = buf[tid ^ j]; cmpex64(key, o, tid, j, k); }
    };
    auto shfp = [&](int k, int j) {
      if (tid < SCAP) { u64 o = shflx_u64(key, j); cmpex64(key, o, tid, j, k); }
    };
    for (int k = 2; k <= 64; k <<= 1)
      for (int j = k >> 1; j >= 1; j >>= 1) shfp(k, j);
    ldsp(128, 64);
    for (int j = 32; j >= 1; j >>= 1) shfp(128, j);
    ldsp(256, 128); ldsp(256, 64);
    for (int j = 32; j >= 1; j >>= 1) shfp(256, j);
    ldsp(512, 256); ldsp(512, 128); ldsp(512, 64);
    for (int j = 32; j >= 1; j >>= 1) shfp(512, j);
    if (tid < SCAP) skeyW64[tid] = key;
    __syncthreads();

    // ---- staged greedy NMS over this window's Csel sorted rows ----
    for (int base = 0; base < Csel && sc < Kcap; base += SBLK) {
      int RL = Csel - base; if (RL > SBLK) RL = SBLK;
      // gather stage boxes
      if (tid < SBLK) {
        int p = base + tid; if (p > Csel - 1) p = Csel - 1;
        u64 kq = skeyW64[p];
        float4 b = decoded[(u32)kq];
        bx0[tid] = b.x; by0[tid] = b.y; bx1[tid] = b.z; by1[tid] = b.w;
        areaA[tid] = __fmul_rn(__fsub_rn(b.z, b.x), __fsub_rn(b.w, b.y));
      }
      if (tid < 4) remInitW[tid] = 0ULL;
      __syncthreads();

      // column-kill vs all existing survivors (waves 0-3)
      if (sc > 0 && tid < SBLK) {
        float jx0 = bx0[tid], jy0 = by0[tid], jx1 = bx1[tid], jy1 = by1[tid];
        float ab = areaA[tid];
        bool kill = false;
        for (int u = 0; u < sc; ++u) {
          float ix0 = sx0[u], iy0 = sy0[u], ix1 = sx1[u], iy1 = sy1[u];
          float ia = sarea[u];
          float lx = fmaxf(ix0, jx0), ly = fmaxf(iy0, jy0);
          float rx = fminf(ix1, jx1), ry = fminf(iy1, jy1);
          float w_ = fmaxf(__fsub_rn(rx, lx), 0.0f);
          float h_ = fmaxf(__fsub_rn(ry, ly), 0.0f);
          float inter = __fmul_rn(w_, h_);
          float iou = __fdiv_rn(inter, __fsub_rn(__fadd_rn(ia, ab), inter));
          kill = kill || (iou > ovr);
        }
        u64 bal = __ballot(kill);
        if (lane == 0) remInitW[wid] = bal;
      }

      // build upper-triangle suppression bit matrix for RL rows
      {
        int nw = (RL + 63) >> 6;
        for (int r2 = wid; r2 < RL; r2 += 16) {
          float ix0 = bx0[r2], iy0 = by0[r2], ix1 = bx1[r2], iy1 = by1[r2];
          float ia = areaA[r2];
          for (int ct = (r2 >> 6); ct < nw; ++ct) {
            int j = (ct << 6) + lane;
            float jx0 = bx0[j], jy0 = by0[j], jx1 = bx1[j], jy1 = by1[j];
            float ab = areaA[j];
            float lx = fmaxf(ix0, jx0), ly = fmaxf(iy0, jy0);
            float rx = fminf(ix1, jx1), ry = fminf(iy1, jy1);
            float w_ = fmaxf(__fsub_rn(rx, lx), 0.0f);
            float h_ = fmaxf(__fsub_rn(ry, ly), 0.0f);
            float inter = __fmul_rn(w_, h_);
            float iou = __fdiv_rn(inter, __fsub_rn(__fadd_rn(ia, ab), inter));
            bool bit = iou > ovr;
            if (ct == (r2 >> 6)) bit = bit && (j > r2);
            u64 bal = __ballot(bit);
            if (lane == 0) maskW[(r2 << 2) + ct] = bal;
          }
        }
      }
      __syncthreads();

      // sweep: iterate alive rows only (alive-when-reached == survivor)
      if (wid == 0) {
        int t0 = RL;
        u64 rw0 = (t0 <= 0) ? ~0ULL : ((t0 >= 64) ? 0ULL : (~0ULL << t0));
        int t1 = t0 - 64;
        u64 rw1 = (t1 <= 0) ? ~0ULL : ((t1 >= 64) ? 0ULL : (~0ULL << t1));
        int t2 = t0 - 128;
        u64 rw2 = (t2 <= 0) ? ~0ULL : ((t2 >= 64) ? 0ULL : (~0ULL << t2));
        int t3 = t0 - 192;
        u64 rw3 = (t3 <= 0) ? ~0ULL : ((t3 >= 64) ? 0ULL : (~0ULL << t3));
        rw0 |= remInitW[0]; rw1 |= remInitW[1];
        rw2 |= remInitW[2]; rw3 |= remInitW[3];
        int scW = sc;
        bool full = scW >= Kcap;
#define SWEEPG(G, RWG)                                                        \
        if (!full) {                                                          \
          u64 pend = ~(RWG);                                                  \
          while (pend && !full) {                                             \
            int b = __ffsll((long long)pend) - 1;                             \
            int row = ((G) << 6) + b;                                         \
            u64 m0 = maskW[(row << 2) + 0], m1 = maskW[(row << 2) + 1];       \
            u64 m2 = maskW[(row << 2) + 2], m3 = maskW[(row << 2) + 3];       \
            rw0 |= m0; rw1 |= m1; rw2 |= m2; rw3 |= m3;                       \
            pend &= ~(1ULL << b);                                             \
            pend &= ~((G) == 0 ? m0 : (G) == 1 ? m1 : (G) == 2 ? m2 : m3);    \
            u32 hsv = (u32)(skeyW64[base + row] >> 32);                       \
            if (lane == 0) {                                                  \
              survKeyH[scW] = hsv;                                            \
              sx0[scW] = bx0[row]; sy0[scW] = by0[row];                       \
              sx1[scW] = bx1[row]; sy1[scW] = by1[row];                       \
              sarea[scW] = areaA[row];                                        \
            }                                                                 \
            ++scW;                                                            \
            full = scW >= Kcap;                                               \
          }                                                                   \
        }
        SWEEPG(0, rw0) SWEEPG(1, rw1) SWEEPG(2, rw2) SWEEPG(3, rw3)
#undef SWEEPG
        if (lane == 0) scLds = scW;
      }
      __syncthreads();
      sc = scLds;
    }

    minKey = skeyW64[Csel - 1];   // largest processed key (uniform read)
    processed += Csel;
    __syncthreads();
  }

  // ---- emit per-class survivor list (greedy order) ----
  if (tid < CPAD) {
    int o = cls * CPAD + tid;
    if (tid < sc) {
      cand[o] = ((u64)survKeyH[tid] << 32) | (u32)o;  // low32 == tie-order
      cbox[o] = make_float4(sx0[tid], sy0[tid], sx1[tid], sy1[tid]);
    } else {
      cand[o] = ~0ULL;
    }
  }

  // ---- signal completion; last block does the global top-K ----
  __threadfence();
  __syncthreads();
  if (tid == 0) lastSh = atomicAdd(done, 1u);
  __syncthreads();
  if (lastSh != NFG - 1) return;
  __threadfence();

  u64* kk = (u64*)LDSW;            // overlay (sort/mask regions dead)
  u64* ck = (u64*)(LDSW + 5120);   // overlay stage SoA (dead)
  if (tid == 0) cCnt = 0;
  if (tid < 256) { hist1[tid] = 0; hist2[tid] = 0; }
  __syncthreads();
  for (int t = tid; t < CTOT; t += NTHR) {
    u64 v = cand[t];
    kk[t] = v;
    if (v != ~0ULL) atomicAdd(&hist1[(int)(v >> 56)], 1);
  }
  __syncthreads();
  if (wid == 0) {                  // M = total valid count (wave reduce)
    int b4 = lane << 2;
    int s = hist1[b4] + hist1[b4 + 1] + hist1[b4 + 2] + hist1[b4 + 3];
    #pragma unroll
    for (int off = 32; off; off >>= 1) s += __shfl_xor(s, off);
    if (lane == 0) mSh = s;
  }
  __syncthreads();
  const int M = mSh;
  const int Kneed = (K < M) ? K : M;

  if (Kneed > 0) {
    if (wid == 0) bucket_select(hist1, Kneed, lane, &selB1, &selC1);
    __syncthreads();
    const int B1 = selB1, C1 = selC1;
    for (int t = tid; t < CTOT; t += NTHR) {
      u64 v = kk[t];
      if (v != ~0ULL && (int)(v >> 56) == B1)
        atomicAdd(&hist2[(int)((v >> 48) & 255)], 1);
    }
    __syncthreads();
    if (wid == 0) bucket_select(hist2, Kneed - C1, lane, &selB2, &selD2);
    __syncthreads();
    const int B2 = selB2;
    for (int t = tid; t < CTOT; t += NTHR) {   // compact contenders
      u64 v = kk[t];
      if (v == ~0ULL) continue;
      int b1 = (int)(v >> 56);
      int b2 = (int)((v >> 48) & 255);
      if (b1 < B1 || (b1 == B1 && b2 <= B2)) {
        int pos = atomicAdd(&cCnt, 1);
        if (pos < CSEL) ck[pos] = v;
      }
    }
    __syncthreads();
    const int C = cCnt;
    if (C <= CSEL) {
      // contender set downward-closed -> in-set rank == global rank
      if (tid < C) {
        u64 my = ck[tid];
        int rank = 0;
        for (int u = 0; u < C; ++u) rank += (ck[u] < my) ? 1 : 0;
        if (rank < K) {
          u32 flat = (u32)(my & 0xFFFFFFFFu);
          float score = key_to_float((u32)(my >> 32));
          int c2 = (int)(flat >> 7);
          float4 b = cbox[flat];
          out[rank * 4 + 0] = b.x;
          out[rank * 4 + 1] = b.y;
          out[rank * 4 + 2] = b.z;
          out[rank * 4 + 3] = b.w;
          out[K * 4 + rank] = (float)(c2 + 1);
          out[K * 5 + rank] = score;
        }
      }
    } else {
      // fallback: exact rank via 20 per-class binary searches
      for (int t = tid; t < CTOT; t += NTHR) {
        u64 kap = kk[t];
        if (kap == ~0ULL) continue;
        int rank = 0;
        #pragma unroll
        for (int cc2 = 0; cc2 < NFG; ++cc2) {
          const u64* a = kk + cc2 * CPAD;
          int lb = 0;
          #pragma unroll
          for (int s2 = CPAD >> 1; s2; s2 >>= 1) {
            int pq = lb + s2;
            if (a[pq - 1] < kap) lb = pq;
          }
          rank += lb;
        }
        if (rank < K) {
          u32 flat = (u32)(kap & 0xFFFFFFFFu);
          float score = key_to_float((u32)(kap >> 32));
          int c2 = (int)(flat >> 7);
          float4 b = cbox[flat];
          out[rank * 4 + 0] = b.x;
          out[rank * 4 + 1] = b.y;
          out[rank * 4 + 2] = b.z;
          out[rank * 4 + 3] = b.w;
          out[K * 4 + rank] = (float)(c2 + 1);
          out[K * 5 + rank] = score;
        }
      }
    }
  }
  __syncthreads();
  for (int r = tid; r < K; r += NTHR) {
    if (r >= M) {
      out[r * 4 + 0] = 0.0f; out[r * 4 + 1] = 0.0f;
      out[r * 4 + 2] = 1.0f; out[r * 4 + 3] = 1.0f;
      out[K * 4 + r] = 0.0f;
      out[K * 5 + r] = 0.0f;
    }
  }
}

// ---- launch ---------------------------------------------------------------
extern "C" void kernel_launch(void* const* d_in, const int* in_sizes, int n_in,
                              void* d_out, int out_size, void* d_ws, size_t ws_size,
                              hipStream_t stream) {
  const float* rois        = (const float*)d_in[0];
  const float* locs        = (const float*)d_in[1];
  const float* scores      = (const float*)d_in[2];
  const float* min_score   = (const float*)d_in[3];
  const float* max_overlap = (const float*)d_in[4];
  const int*   top_k       = (const int*)d_in[5];

  char* ws = (char*)d_ws;
  // layout: cand 2560*8 | cbox 2560*16 | probsT 20*2048*4 | decoded 2048*16 | done 4
  u64*    cand    = (u64*)ws;
  float4* cbox    = (float4*)(ws + 20480);
  float*  probsT  = (float*)(ws + 20480 + 40960);
  float4* decoded = (float4*)(ws + 20480 + 40960 + 163840);
  u32*    done    = (u32*)(ws + 20480 + 40960 + 163840 + 32768);

  k_decode<<<NROI / DROWS, 64, 0, stream>>>(rois, locs, scores, probsT, decoded, done);
  k_nms<<<NFG, NTHR, 0, stream>>>(probsT, decoded, min_score, max_overlap,
                                  cand, cbox, done, (float*)d_out, top_k);
}

// Round 11
// 58.201 us; speedup vs baseline: 3.1197x; 1.1860x over previous
//
#include <hip/hip_runtime.h>
#include <cstdint>

#define NROI 2048
#define NCLS 21
#define NFG  20
#define CPAD 128          // survivor slots per class (>= top_k=100)
#define CTOT (NFG * CPAD) // 2560
#define NTHR 1024         // threads per NMS block (16 waves)
#define SBLK 256          // rows per NMS stage
#define RSEL 480          // selection rank target per window
#define SCAP 512          // selection capacity (sorted window size)
#define CSEL 512          // contender cap for top-k rank-count
#define DROWS 64          // rows per decode block
#define INVH 0xFF800000u  // desc_key(-inf) == invalid marker

typedef unsigned long long u64;
typedef unsigned int u32;

// ---- sortable key helpers -------------------------------------------------
// desc_key(s): larger float -> smaller uint, so ascending sort on
// u64 key = (desc_key(score)<<32)|index == (score desc, index asc).
__device__ __forceinline__ u32 desc_key(float s) {
  u32 u = __float_as_uint(s);
  u32 asc = (u & 0x80000000u) ? ~u : (u | 0x80000000u);
  return ~asc;
}
__device__ __forceinline__ float key_to_float(u32 desc) {
  u32 asc = ~desc;
  u32 u = (asc & 0x80000000u) ? (asc ^ 0x80000000u) : ~asc;
  return __uint_as_float(u);
}
__device__ __forceinline__ u64 shflx_u64(u64 v, int m) {
  u32 lo = (u32)v, hi = (u32)(v >> 32);
  lo = (u32)__shfl_xor((int)lo, m);
  hi = (u32)__shfl_xor((int)hi, m);
  return ((u64)hi << 32) | (u64)lo;
}
// bitonic compare-exchange for element i at pass (k, j), u64 lex order
__device__ __forceinline__ void cmpex64(u64& mine, u64 other, int i, int j, int k) {
  bool amIlow = ((i & j) == 0);
  bool dir = ((i & k) == 0);
  bool otherLess = other < mine;
  if (otherLess != (amIlow != dir)) mine = other;
}

// wave-0 parallel 256-bin bucket select: smallest bucket b with
// cum(h[0..b]) >= need; *outC = cum before b. (1 <= need <= total)
__device__ __forceinline__ void bucket_select(const int* h, int need, int lane,
                                              int* outB, int* outC) {
  int base = lane << 2;
  int c0 = h[base], c1 = h[base + 1], c2 = h[base + 2], c3 = h[base + 3];
  int s = c0 + c1 + c2 + c3;
  int pre = s;
  #pragma unroll
  for (int off = 1; off < 64; off <<= 1) {
    int v = __shfl_up(pre, off);
    if (lane >= off) pre += v;
  }
  u64 ball = __ballot(pre >= need);
  int ln = __ffsll((long long)ball) - 1;
  int exc = __shfl(pre, ln) - __shfl(s, ln);
  int b0 = __shfl(c0, ln), b1 = __shfl(c1, ln), b2 = __shfl(c2, ln);
  int bkt, cb;
  if (exc + b0 >= need)                { bkt = (ln << 2) + 0; cb = exc; }
  else if (exc + b0 + b1 >= need)      { bkt = (ln << 2) + 1; cb = exc + b0; }
  else if (exc + b0 + b1 + b2 >= need) { bkt = (ln << 2) + 2; cb = exc + b0 + b1; }
  else                                 { bkt = (ln << 2) + 3; cb = exc + b0 + b1 + b2; }
  if (lane == 0) { *outB = bkt; *outC = cb; }
}

// ---- phase 1: coalesced softmax + argmax + decode (32 blocks x 64 thr) ----
__global__ __launch_bounds__(64)
void k_decode(const float* __restrict__ rois,
              const float* __restrict__ locs,
              const float* __restrict__ scores,
              float* __restrict__ probsT,     // [NFG][NROI]: class c+1 -> row c
              float4* __restrict__ decoded,
              u32* __restrict__ done) {
  __shared__ float srow[DROWS][NCLS + 2];   // stride 23 (odd) -> conflict-free
  const int tid = threadIdx.x;
  const int rbase = blockIdx.x * DROWS;
  if (rbase == 0 && tid == 0) *done = 0u;   // reset last-block counter each launch

  const float* src = scores + (size_t)rbase * NCLS;
  for (int t = tid; t < DROWS * NCLS; t += 64)
    srow[t / NCLS][t % NCLS] = src[t];
  __syncthreads();

  const int r = rbase + tid;
  float s[NCLS];
  #pragma unroll
  for (int c = 0; c < NCLS; ++c) s[c] = srow[tid][c];
  float m = s[0];
  #pragma unroll
  for (int c = 0; c < NCLS; ++c) m = fmaxf(m, s[c]);
  float sum = 0.0f;
  #pragma unroll
  for (int c = 0; c < NCLS; ++c) { s[c] = expf(s[c] - m); sum += s[c]; }

  float pb = s[0] / sum; int best = 0;
  #pragma unroll
  for (int c = 1; c < NCLS; ++c) {
    float p = s[c] / sum;
    probsT[(c - 1) * NROI + r] = p;        // coalesced store per class
    if (p > pb) { pb = p; best = c; }      // strict > == first-index argmax
  }

  float4 roi = ((const float4*)rois)[r];
  float pcx = __fmul_rn(__fadd_rn(roi.x, roi.z), 0.5f);
  float pcy = __fmul_rn(__fadd_rn(roi.y, roi.w), 0.5f);
  float pw  = __fsub_rn(roi.z, roi.x);
  float ph  = __fsub_rn(roi.w, roi.y);

  float4 gl = ((const float4*)locs)[r * NCLS + best];   // 16B-aligned
  float g0 = gl.x / 10.0f;
  float g1 = gl.y / 10.0f;
  float g2 = gl.z / 20.0f;
  float g3 = gl.w / 20.0f;

  // no-FMA-contraction decode to match numpy rounding
  float cx = __fadd_rn(__fmul_rn(g0, pw), pcx);
  float cy = __fadd_rn(__fmul_rn(g1, ph), pcy);
  float w  = __fmul_rn(expf(g2), pw);
  float h  = __fmul_rn(expf(g3), ph);
  float hw = __fmul_rn(w, 0.5f);
  float hh = __fmul_rn(h, 0.5f);
  decoded[r] = make_float4(__fsub_rn(cx, hw), __fsub_rn(cy, hh),
                           __fadd_rn(cx, hw), __fadd_rn(cy, hh));
}

// ---- phase 2: select+sort window -> staged bitmask NMS -> last-block topk -
__global__ __launch_bounds__(NTHR)
void k_nms(const float* __restrict__ probsT,
           const float4* __restrict__ decoded,
           const float* __restrict__ min_score_p,
           const float* __restrict__ max_overlap_p,
           u64* __restrict__ cand,
           float4* __restrict__ cbox,
           u32* __restrict__ done,
           float* __restrict__ out,
           const int* __restrict__ top_k_p) {
  // LDS word map (u32), ~29 KB total:
  //  [0,1024)     mbA u64[512]        (sort mailbox A; tail: kk[0..])
  //  [1024,2048)  mbB u64[512]        (sort mailbox B)
  //  [2048,3072)  skeyW u64[512]      (sorted window keys)
  //  [3072,5120)  maskW u64[256*4]
  //  [5120,6400)  stage SoA bx0/by0/bx1/by1/areaA [256] each   (tail: ck@5120)
  //  [6400,7040)  surv SoA sx0/sy0/sx1/sy1/sarea [128] each
  //  [7040,7168)  survKeyH[128]
  //  [7168,7296)  survRows[128]
  __shared__ u32 LDSW[7296];
  __shared__ u64 remInitW[4];
  __shared__ int hist1[256], hist2[256];
  __shared__ int cntLds, scLds, cSelSh, selB1, selC1, selB2, selD2, mSh, cCnt;
  __shared__ u32 lastSh;

  u64* mbAu    = (u64*)(LDSW + 0);
  u64* mbBu    = (u64*)(LDSW + 1024);
  u64* skeyW64 = (u64*)(LDSW + 2048);
  u64* maskW   = (u64*)(LDSW + 3072);
  float* bx0   = (float*)(LDSW + 5120);
  float* by0   = (float*)(LDSW + 5376);
  float* bx1   = (float*)(LDSW + 5632);
  float* by1   = (float*)(LDSW + 5888);
  float* areaA = (float*)(LDSW + 6144);
  float* sx0   = (float*)(LDSW + 6400);
  float* sy0   = (float*)(LDSW + 6528);
  float* sx1   = (float*)(LDSW + 6656);
  float* sy1   = (float*)(LDSW + 6784);
  float* sarea = (float*)(LDSW + 6912);
  u32* survKeyH = LDSW + 7040;
  u32* survRows = LDSW + 7168;

  const int cls = blockIdx.x;
  const int tid = threadIdx.x;
  const int lane = tid & 63;
  const int wid = tid >> 6;
  const float msc = *min_score_p;
  const float ovr = *max_overlap_p;
  const int K = *top_k_p;
  const int Kcap = (K < CPAD) ? K : CPAD;

  if (tid == 0) { cntLds = 0; scLds = 0; }
  __syncthreads();

  // ---- per-thread keys (2 rows each) + valid count ----
  float p0v = probsT[cls * NROI + tid];
  float p1v = probsT[cls * NROI + tid + 1024];
  bool v0 = p0v > msc, v1 = p1v > msc;
  u64 kq0 = ((u64)desc_key(v0 ? p0v : -__builtin_inff()) << 32) | (u32)tid;
  u64 kq1 = ((u64)desc_key(v1 ? p1v : -__builtin_inff()) << 32) | (u32)(tid + 1024);
  {
    u64 ba = __ballot(v0), bb = __ballot(v1);
    if (lane == 0) atomicAdd(&cntLds, __popcll(ba) + __popcll(bb));
  }
  __syncthreads();
  const int nv = cntLds;

  int sc = 0;
  int processed = 0;
  u64 minKey = 0ULL;   // exclusive lower bound of already-processed keys

  // ================= selection-window loop (1 window typical) =============
  while (sc < Kcap && processed < nv) {
    int rem = nv - processed;
    int need = (rem < RSEL) ? rem : RSEL;

    // ---- 2-level histogram threshold select (exact, prefix-closed) ----
    if (tid < 256) { hist1[tid] = 0; hist2[tid] = 0; }
    if (tid == 0) cSelSh = 0;
    __syncthreads();
    bool val0 = (kq0 > minKey) && ((u32)(kq0 >> 32) < INVH);
    bool val1 = (kq1 > minKey) && ((u32)(kq1 >> 32) < INVH);
    if (val0) atomicAdd(&hist1[(int)((kq0 >> 56) & 255)], 1);
    if (val1) atomicAdd(&hist1[(int)((kq1 >> 56) & 255)], 1);
    __syncthreads();
    if (wid == 0) bucket_select(hist1, need, lane, &selB1, &selC1);
    __syncthreads();
    const int B1 = selB1, C1 = selC1;
    if (val0 && (int)((kq0 >> 56) & 255) == B1)
      atomicAdd(&hist2[(int)((kq0 >> 48) & 255)], 1);
    if (val1 && (int)((kq1 >> 56) & 255) == B1)
      atomicAdd(&hist2[(int)((kq1 >> 48) & 255)], 1);
    __syncthreads();
    if (wid == 0) bucket_select(hist2, need - C1, lane, &selB2, &selD2);
    __syncthreads();
    const int pred16 = (selB1 << 8) | selB2;

    // ---- compact selected keys (order irrelevant; sorted next) ----
    bool s0 = val0 && (int)((kq0 >> 48) & 0xFFFF) <= pred16;
    bool s1 = val1 && (int)((kq1 >> 48) & 0xFFFF) <= pred16;
    {
      u64 b0 = __ballot(s0), b1 = __ballot(s1);
      int cnt = __popcll(b0) + __popcll(b1);
      int basePos = 0;
      if (lane == 0) basePos = cnt ? atomicAdd(&cSelSh, cnt) : 0;
      basePos = __shfl(basePos, 0);
      u64 lm = (1ULL << lane) - 1ULL;
      int p0 = basePos + __popcll(b0 & lm);
      int p1 = basePos + __popcll(b0) + __popcll(b1 & lm);
      if (s0 && p0 < SCAP) mbAu[p0] = kq0;
      if (s1 && p1 < SCAP) mbAu[p1] = kq1;
    }
    __syncthreads();
    int Csel = cSelSh; if (Csel > SCAP) Csel = SCAP;  // clamp (float-continuous
                                                      // scores: never overflows)
    if (tid < SCAP && tid >= Csel) mbAu[tid] = ~0ULL;
    __syncthreads();

    // ---- bitonic sort 512 (threads<512 hold 1 element; pad sorts last) ----
    u64 key = (tid < SCAP) ? mbAu[tid] : ~0ULL;
    int parity = 0;
    auto ldsp = [&](int k, int j) {
      u64* buf = parity ? mbBu : mbAu; parity ^= 1;
      if (tid < SCAP) buf[tid] = key;
      __syncthreads();
      if (tid < SCAP) { u64 o = buf[tid ^ j]; cmpex64(key, o, tid, j, k); }
    };
    auto shfp = [&](int k, int j) {
      if (tid < SCAP) { u64 o = shflx_u64(key, j); cmpex64(key, o, tid, j, k); }
    };
    for (int k = 2; k <= 64; k <<= 1)
      for (int j = k >> 1; j >= 1; j >>= 1) shfp(k, j);
    ldsp(128, 64);
    for (int j = 32; j >= 1; j >>= 1) shfp(128, j);
    ldsp(256, 128); ldsp(256, 64);
    for (int j = 32; j >= 1; j >>= 1) shfp(256, j);
    ldsp(512, 256); ldsp(512, 128); ldsp(512, 64);
    for (int j = 32; j >= 1; j >>= 1) shfp(512, j);
    if (tid < SCAP) skeyW64[tid] = key;
    __syncthreads();

    // ---- staged greedy NMS over this window's Csel sorted rows ----
    for (int base = 0; base < Csel && sc < Kcap; base += SBLK) {
      int RL = Csel - base; if (RL > SBLK) RL = SBLK;
      // gather stage boxes
      if (tid < SBLK) {
        int p = base + tid; if (p > Csel - 1) p = Csel - 1;
        u64 kq = skeyW64[p];
        float4 b = decoded[(u32)kq];
        bx0[tid] = b.x; by0[tid] = b.y; bx1[tid] = b.z; by1[tid] = b.w;
        areaA[tid] = __fmul_rn(__fsub_rn(b.z, b.x), __fsub_rn(b.w, b.y));
      }
      if (tid < 4) remInitW[tid] = 0ULL;
      __syncthreads();

      // column-kill vs all existing survivors (waves 0-3)
      if (sc > 0 && tid < SBLK) {
        float jx0 = bx0[tid], jy0 = by0[tid], jx1 = bx1[tid], jy1 = by1[tid];
        float ab = areaA[tid];
        bool kill = false;
        for (int u = 0; u < sc; ++u) {
          float ix0 = sx0[u], iy0 = sy0[u], ix1 = sx1[u], iy1 = sy1[u];
          float ia = sarea[u];
          float lx = fmaxf(ix0, jx0), ly = fmaxf(iy0, jy0);
          float rx = fminf(ix1, jx1), ry = fminf(iy1, jy1);
          float w_ = fmaxf(__fsub_rn(rx, lx), 0.0f);
          float h_ = fmaxf(__fsub_rn(ry, ly), 0.0f);
          float inter = __fmul_rn(w_, h_);
          float iou = __fdiv_rn(inter, __fsub_rn(__fadd_rn(ia, ab), inter));
          kill = kill || (iou > ovr);
        }
        u64 bal = __ballot(kill);
        if (lane == 0) remInitW[wid] = bal;
      }
      __syncthreads();   // publish remInitW so mask build can skip dead rows

      // build upper-triangle suppression bit matrix (dead rows skipped:
      // a dead row's mask is never OR'd by the sweep)
      {
        int nw = (RL + 63) >> 6;
        for (int r2 = wid; r2 < RL; r2 += 16) {
          if ((remInitW[r2 >> 6] >> (r2 & 63)) & 1ULL) continue;
          float ix0 = bx0[r2], iy0 = by0[r2], ix1 = bx1[r2], iy1 = by1[r2];
          float ia = areaA[r2];
          for (int ct = (r2 >> 6); ct < nw; ++ct) {
            int j = (ct << 6) + lane;
            float jx0 = bx0[j], jy0 = by0[j], jx1 = bx1[j], jy1 = by1[j];
            float ab = areaA[j];
            float lx = fmaxf(ix0, jx0), ly = fmaxf(iy0, jy0);
            float rx = fminf(ix1, jx1), ry = fminf(iy1, jy1);
            float w_ = fmaxf(__fsub_rn(rx, lx), 0.0f);
            float h_ = fmaxf(__fsub_rn(ry, ly), 0.0f);
            float inter = __fmul_rn(w_, h_);
            float iou = __fdiv_rn(inter, __fsub_rn(__fadd_rn(ia, ab), inter));
            bool bit = iou > ovr;
            if (ct == (r2 >> 6)) bit = bit && (j > r2);
            u64 bal = __ballot(bit);
            if (lane == 0) maskW[(r2 << 2) + ct] = bal;
          }
        }
      }
      __syncthreads();

      // ---- sweep: linear scan, 4-row register prefetch (no dependent
      //      loads; per-row cost = bit test + 4 ORs) ----
      if (wid == 0) {
        int t0 = RL;
        u64 rw0 = (t0 <= 0) ? ~0ULL : ((t0 >= 64) ? 0ULL : (~0ULL << t0));
        int t1 = t0 - 64;
        u64 rw1 = (t1 <= 0) ? ~0ULL : ((t1 >= 64) ? 0ULL : (~0ULL << t1));
        int t2 = t0 - 128;
        u64 rw2 = (t2 <= 0) ? ~0ULL : ((t2 >= 64) ? 0ULL : (~0ULL << t2));
        int t3 = t0 - 192;
        u64 rw3 = (t3 <= 0) ? ~0ULL : ((t3 >= 64) ? 0ULL : (~0ULL << t3));
        rw0 |= remInitW[0]; rw1 |= remInitW[1];
        rw2 |= remInitW[2]; rw3 |= remInitW[3];
        int scW = sc;
        bool full = scW >= Kcap;
        u64 a00,a01,a02,a03,a10,a11,a12,a13,a20,a21,a22,a23,a30,a31,a32,a33;
        u64 b00,b01,b02,b03,b10,b11,b12,b13,b20,b21,b22,b23,b30,b31,b32,b33;
#define LD4(V0,V1,V2,V3,R) { int rr_ = (R); \
        V0 = maskW[(rr_<<2)+0]; V1 = maskW[(rr_<<2)+1]; \
        V2 = maskW[(rr_<<2)+2]; V3 = maskW[(rr_<<2)+3]; }
#define PRX(RWG, BIT, M0,M1,M2,M3, ROW) \
        if (!full && !(((RWG) >> (BIT)) & 1ULL)) { \
          rw0 |= (M0); rw1 |= (M1); rw2 |= (M2); rw3 |= (M3); \
          if (lane == 0) survRows[scW] = (u32)(base + (ROW)); \
          ++scW; full = (scW >= Kcap); \
        }
#define SWEEPG(G, RWG) \
        if (!full && (((G) << 6) < RL)) { \
          const int rb = (G) << 6; \
          LD4(a00,a01,a02,a03, rb+0) LD4(a10,a11,a12,a13, rb+1) \
          LD4(a20,a21,a22,a23, rb+2) LD4(a30,a31,a32,a33, rb+3) \
          for (int bb = 0; bb < 64 && !full; bb += 4) { \
            LD4(b00,b01,b02,b03, rb+bb+4) LD4(b10,b11,b12,b13, rb+bb+5) \
            LD4(b20,b21,b22,b23, rb+bb+6) LD4(b30,b31,b32,b33, rb+bb+7) \
            PRX(RWG, bb+0, a00,a01,a02,a03, rb+bb+0) \
            PRX(RWG, bb+1, a10,a11,a12,a13, rb+bb+1) \
            PRX(RWG, bb+2, a20,a21,a22,a23, rb+bb+2) \
            PRX(RWG, bb+3, a30,a31,a32,a33, rb+bb+3) \
            a00=b00;a01=b01;a02=b02;a03=b03; a10=b10;a11=b11;a12=b12;a13=b13; \
            a20=b20;a21=b21;a22=b22;a23=b23; a30=b30;a31=b31;a32=b32;a33=b33; \
          } \
        }
        SWEEPG(0, rw0) SWEEPG(1, rw1) SWEEPG(2, rw2) SWEEPG(3, rw3)
#undef SWEEPG
#undef PRX
#undef LD4
        if (lane == 0) scLds = scW;
      }
      __syncthreads();

      // parallel survivor fill (off the serial sweep path)
      {
        int scNew = scLds;
        if (tid >= sc && tid < scNew) {
          int wrow = (int)survRows[tid];
          int rr = wrow - base;          // this stage's local row
          sx0[tid] = bx0[rr]; sy0[tid] = by0[rr];
          sx1[tid] = bx1[rr]; sy1[tid] = by1[rr];
          sarea[tid] = areaA[rr];
          survKeyH[tid] = (u32)(skeyW64[wrow] >> 32);
        }
        __syncthreads();   // surv SoA complete before next stage / emit
        sc = scNew;
      }
    }

    minKey = skeyW64[Csel - 1];   // largest processed key (uniform read)
    processed += Csel;
    __syncthreads();
  }

  // ---- emit per-class survivor list (greedy order) ----
  if (tid < CPAD) {
    int o = cls * CPAD + tid;
    if (tid < sc) {
      cand[o] = ((u64)survKeyH[tid] << 32) | (u32)o;  // low32 == tie-order
      cbox[o] = make_float4(sx0[tid], sy0[tid], sx1[tid], sy1[tid]);
    } else {
      cand[o] = ~0ULL;
    }
  }

  // ---- signal completion; last block does the global top-K ----
  __threadfence();
  __syncthreads();
  if (tid == 0) lastSh = atomicAdd(done, 1u);
  __syncthreads();
  if (lastSh != NFG - 1) return;
  __threadfence();

  u64* kk = (u64*)LDSW;            // overlay (sort/mask regions dead)
  u64* ck = (u64*)(LDSW + 5120);   // overlay stage SoA (dead)
  if (tid == 0) cCnt = 0;
  if (tid < 256) { hist1[tid] = 0; hist2[tid] = 0; }
  __syncthreads();
  for (int t = tid; t < CTOT; t += NTHR) {
    u64 v = cand[t];
    kk[t] = v;
    if (v != ~0ULL) atomicAdd(&hist1[(int)(v >> 56)], 1);
  }
  __syncthreads();
  if (wid == 0) {                  // M = total valid count (wave reduce)
    int b4 = lane << 2;
    int s = hist1[b4] + hist1[b4 + 1] + hist1[b4 + 2] + hist1[b4 + 3];
    #pragma unroll
    for (int off = 32; off; off >>= 1) s += __shfl_xor(s, off);
    if (lane == 0) mSh = s;
  }
  __syncthreads();
  const int M = mSh;
  const int Kneed = (K < M) ? K : M;

  if (Kneed > 0) {
    if (wid == 0) bucket_select(hist1, Kneed, lane, &selB1, &selC1);
    __syncthreads();
    const int B1 = selB1, C1 = selC1;
    for (int t = tid; t < CTOT; t += NTHR) {
      u64 v = kk[t];
      if (v != ~0ULL && (int)(v >> 56) == B1)
        atomicAdd(&hist2[(int)((v >> 48) & 255)], 1);
    }
    __syncthreads();
    if (wid == 0) bucket_select(hist2, Kneed - C1, lane, &selB2, &selD2);
    __syncthreads();
    const int B2 = selB2;
    for (int t = tid; t < CTOT; t += NTHR) {   // compact contenders
      u64 v = kk[t];
      if (v == ~0ULL) continue;
      int b1 = (int)(v >> 56);
      int b2 = (int)((v >> 48) & 255);
      if (b1 < B1 || (b1 == B1 && b2 <= B2)) {
        int pos = atomicAdd(&cCnt, 1);
        if (pos < CSEL) ck[pos] = v;
      }
    }
    __syncthreads();
    const int C = cCnt;
    if (C <= CSEL) {
      // contender set downward-closed -> in-set rank == global rank
      if (tid < C) {
        u64 my = ck[tid];
        int rank = 0;
        for (int u = 0; u < C; ++u) rank += (ck[u] < my) ? 1 : 0;
        if (rank < K) {
          u32 flat = (u32)(my & 0xFFFFFFFFu);
          float score = key_to_float((u32)(my >> 32));
          int c2 = (int)(flat >> 7);
          float4 b = cbox[flat];
          out[rank * 4 + 0] = b.x;
          out[rank * 4 + 1] = b.y;
          out[rank * 4 + 2] = b.z;
          out[rank * 4 + 3] = b.w;
          out[K * 4 + rank] = (float)(c2 + 1);
          out[K * 5 + rank] = score;
        }
      }
    } else {
      // fallback: exact rank via 20 per-class binary searches
      for (int t = tid; t < CTOT; t += NTHR) {
        u64 kap = kk[t];
        if (kap == ~0ULL) continue;
        int rank = 0;
        #pragma unroll
        for (int cc2 = 0; cc2 < NFG; ++cc2) {
          const u64* a = kk + cc2 * CPAD;
          int lb = 0;
          #pragma unroll
          for (int s2 = CPAD >> 1; s2; s2 >>= 1) {
            int pq = lb + s2;
            if (a[pq - 1] < kap) lb = pq;
          }
          rank += lb;
        }
        if (rank < K) {
          u32 flat = (u32)(kap & 0xFFFFFFFFu);
          float score = key_to_float((u32)(kap >> 32));
          int c2 = (int)(flat >> 7);
          float4 b = cbox[flat];
          out[rank * 4 + 0] = b.x;
          out[rank * 4 + 1] = b.y;
          out[rank * 4 + 2] = b.z;
          out[rank * 4 + 3] = b.w;
          out[K * 4 + rank] = (float)(c2 + 1);
          out[K * 5 + rank] = score;
        }
      }
    }
  }
  __syncthreads();
  for (int r = tid; r < K; r += NTHR) {
    if (r >= M) {
      out[r * 4 + 0] = 0.0f; out[r * 4 + 1] = 0.0f;
      out[r * 4 + 2] = 1.0f; out[r * 4 + 3] = 1.0f;
      out[K * 4 + r] = 0.0f;
      out[K * 5 + r] = 0.0f;
    }
  }
}

// ---- launch ---------------------------------------------------------------
extern "C" void kernel_launch(void* const* d_in, const int* in_sizes, int n_in,
                              void* d_out, int out_size, void* d_ws, size_t ws_size,
                              hipStream_t stream) {
  const float* rois        = (const float*)d_in[0];
  const float* locs        = (const float*)d_in[1];
  const float* scores      = (const float*)d_in[2];
  const float* min_score   = (const float*)d_in[3];
  const float* max_overlap = (const float*)d_in[4];
  const int*   top_k       = (const int*)d_in[5];

  char* ws = (char*)d_ws;
  // layout: cand 2560*8 | cbox 2560*16 | probsT 20*2048*4 | decoded 2048*16 | done 4
  u64*    cand    = (u64*)ws;
  float4* cbox    = (float4*)(ws + 20480);
  float*  probsT  = (float*)(ws + 20480 + 40960);
  float4* decoded = (float4*)(ws + 20480 + 40960 + 163840);
  u32*    done    = (u32*)(ws + 20480 + 40960 + 163840 + 32768);

  k_decode<<<NROI / DROWS, 64, 0, stream>>>(rois, locs, scores, probsT, decoded, done);
  k_nms<<<NFG, NTHR, 0, stream>>>(probsT, decoded, min_score, max_overlap,
                                  cand, cbox, done, (float*)d_out, top_k);
}